// Round 1
// baseline (1772.132 us; speedup 1.0000x reference)
//
#include <hip/hip_runtime.h>
#include <math.h>

#define T_    2048
#define BTOK  4096   // B * T

namespace {
constexpr int GRADE[16] = {0,1,1,1,1,2,2,2,2,2,2,3,3,3,3,4};
// e0-augmentation: target comp p gets w[k]*x[src]
constexpr int AUGK[16]  = {-1,5,-1,-1,-1,6,6,6,-1,-1,-1,7,7,7,-1,8};
constexpr int AUGS[16]  = { 0,0, 0, 0, 0,2,3,4, 0, 0, 0,8,9,10,0,14};
constexpr float FINNER[16] = {1.f,0.f,1.f,1.f,1.f,0.f,0.f,0.f,1.f,1.f,1.f,0.f,0.f,0.f,1.f,0.f};
}

__device__ __forceinline__ float gelu_f(float v){
  return 0.5f*v*(1.f + erff(v*0.70710678118654752f));
}

// canonical reordering sign for blade bitmasks
__device__ __forceinline__ int rsign_d(int a, int b){
  int s=0; a>>=1; while(a){ s += __popc(a&b); a>>=1; } return (s&1) ? -1 : 1;
}

// Build sparse GP and JOIN tables: per output component k, 16 padded entries
// (i | j<<4, sign). Blade order of the reference <-> bitmask maps hardcoded.
__global__ void build_tables_k(int* __restrict__ gp_ij, float* __restrict__ gp_s,
                               int* __restrict__ jn_ij, float* __restrict__ jn_s){
  const int mask_of[16]={0,1,2,4,8,3,5,9,6,10,12,7,11,13,14,15};
  const int idx_of[16] ={0,1,2,5,3,6,8,11,4,7,9,12,10,13,14,15};
  int t = threadIdx.x;
  if (t < 16){
    int k=t, km=mask_of[k], slot=0;
    for (int i=0;i<16;i++){
      int im=mask_of[i], jm=im^km;
      if (im & jm & 1) continue;              // e0 in common -> metric 0
      gp_ij[k*16+slot] = i | (idx_of[jm]<<4);
      gp_s [k*16+slot] = (float)rsign_d(im,jm);
      slot++;
    }
    for(;slot<16;slot++){ gp_ij[k*16+slot]=0; gp_s[k*16+slot]=0.f; }
  } else if (t < 32){
    int p=t-16, pm=mask_of[p], rest=15&~pm, slot=0;
    for (int u=0;u<16;u++){
      if (u & ~rest) continue;
      int am = pm|u, bm = pm|(rest&~u);       // a&b=pm, a|b=1111
      float s = (float)( rsign_d(pm,15&~pm) * rsign_d(15&~am,15&~bm)
                       * rsign_d(am,15&~am) * rsign_d(bm,15&~bm) );
      jn_ij[p*16+slot] = idx_of[am] | (idx_of[bm]<<4);
      jn_s [p*16+slot] = s;
      slot++;
    }
    for(;slot<16;slot++){ jn_ij[p*16+slot]=0; jn_s[p*16+slot]=0.f; }
  }
}

__device__ __forceinline__ void load_mv8(const float* __restrict__ g, float x[8][16]){
  const float4* g4 = (const float4*)g;
  #pragma unroll
  for (int i=0;i<32;i++){
    float4 v = g4[i];
    x[i>>2][(i&3)*4+0]=v.x; x[i>>2][(i&3)*4+1]=v.y;
    x[i>>2][(i&3)*4+2]=v.z; x[i>>2][(i&3)*4+3]=v.w;
  }
}

// one output channel of equi_linear (mv part), I=8 input channels, w = 8x9 slice
__device__ __forceinline__ void lin_one8(const float x[8][16], const float* __restrict__ w, float y[16]){
  #pragma unroll
  for (int p=0;p<16;p++) y[p]=0.f;
  #pragma unroll
  for (int i=0;i<8;i++){
    const float* wi = w + i*9;
    #pragma unroll
    for (int p=0;p<16;p++){
      float v = wi[GRADE[p]]*x[i][p];
      if (AUGK[p]>=0) v += wi[AUGK[p]]*x[i][AUGS[p]];
      y[p] += v;
    }
  }
}

// ---- K1: embed + input linear + norm -------------------------------------
__global__ void __launch_bounds__(256) k_embed(
    const float* __restrict__ x,
    const float* __restrict__ w_in_mv, const float* __restrict__ b_in_mv,
    const float* __restrict__ w_in_m2s, const float* __restrict__ b_in_s,
    float* __restrict__ h_mv, float* __restrict__ h_s,
    float* __restrict__ n_mv, float* __restrict__ n_s)
{
  int tt = blockIdx.x*256 + threadIdx.x;
  if (tt >= BTOK) return;
  const float* xp = x + (size_t)tt*6;
  float mv[16];
  #pragma unroll
  for (int p=0;p<16;p++) mv[p]=0.f;
  mv[0]=1.f; mv[14]=1.f;
  mv[13]=-xp[0]; mv[12]=xp[1]; mv[11]=-xp[2];
  mv[5]=0.5f*xp[3]; mv[6]=0.5f*xp[4]; mv[7]=0.5f*xp[5];

  float hm[8][16]; float sq=0.f;
  #pragma unroll
  for (int o=0;o<8;o++){
    const float* wo = w_in_mv + o*9;
    #pragma unroll
    for (int p=0;p<16;p++){
      float v = wo[GRADE[p]]*mv[p];
      if (AUGK[p]>=0) v += wo[AUGK[p]]*mv[AUGS[p]];
      if (p==0) v += b_in_mv[o];
      hm[o][p]=v; sq += FINNER[p]*v*v;
    }
  }
  float dmv = rsqrtf(sq*0.125f + 0.01f);
  float hs[24]; float ssq=0.f;
  #pragma unroll
  for (int j=0;j<24;j++){ float v = w_in_m2s[j] + b_in_s[j]; hs[j]=v; ssq+=v*v; }
  float dss = rsqrtf(ssq*(1.f/24.f) + 0.01f);

  size_t base=(size_t)tt*128, bs=(size_t)tt*24;
  #pragma unroll
  for (int o=0;o<8;o++)
    #pragma unroll
    for (int p=0;p<16;p++){ h_mv[base+o*16+p]=hm[o][p]; n_mv[base+o*16+p]=hm[o][p]*dmv; }
  #pragma unroll
  for (int j=0;j<24;j++){ h_s[bs+j]=hs[j]; n_s[bs+j]=hs[j]*dss; }
}

// ---- K2: QKV projections --------------------------------------------------
__device__ __forceinline__ void proj_one(
    int tt, const float xm[8][16], const float xs[24],
    const float* __restrict__ wmv, const float* __restrict__ ws2mv,
    const float* __restrict__ wm2s, const float* __restrict__ ws2s,
    float* __restrict__ om, float* __restrict__ os)
{
  size_t base=(size_t)tt*128;
  #pragma unroll
  for (int o=0;o<8;o++){
    float y[16]; lin_one8(xm, wmv+o*72, y);
    float e=0.f;
    #pragma unroll
    for (int j=0;j<24;j++) e += ws2mv[o*24+j]*xs[j];
    y[0]+=e;
    #pragma unroll
    for (int p=0;p<16;p++) om[base+o*16+p]=y[p];
  }
  size_t bs=(size_t)tt*24;
  #pragma unroll
  for (int d=0;d<24;d++){
    float a=0.f;
    #pragma unroll
    for (int i=0;i<8;i++) a += wm2s[d*8+i]*xm[i][0];
    #pragma unroll
    for (int j=0;j<24;j++) a += ws2s[d*24+j]*xs[j];
    os[bs+d]=a;
  }
}

__global__ void __launch_bounds__(256) k_qkv(
    const float* __restrict__ n_mv, const float* __restrict__ n_s,
    const float* __restrict__ w_mv, const float* __restrict__ w_s2mv,
    const float* __restrict__ w_m2s, const float* __restrict__ w_s2s,
    float* __restrict__ q_mv, float* __restrict__ q_s,
    float* __restrict__ k_mv, float* __restrict__ k_s,
    float* __restrict__ v_mv, float* __restrict__ v_s)
{
  int tt = blockIdx.x*256 + threadIdx.x;
  if (tt >= BTOK) return;
  float xm[8][16]; load_mv8(n_mv+(size_t)tt*128, xm);
  float xs[24];
  #pragma unroll
  for (int j=0;j<24;j++) xs[j]=n_s[(size_t)tt*24+j];
  proj_one(tt,xm,xs, w_mv,      w_s2mv,     w_m2s,     w_s2s,      q_mv,q_s);
  proj_one(tt,xm,xs, w_mv+576,  w_s2mv+192, w_m2s+192, w_s2s+576,  k_mv,k_s);
  proj_one(tt,xm,xs, w_mv+1152, w_s2mv+384, w_m2s+384, w_s2s+1152, v_mv,v_s);
}

// ---- K3: block-causal attention, 1 thread per (b,h,q), online softmax ----
__global__ void __launch_bounds__(256) k_attn(
    const float* __restrict__ q_mv, const float* __restrict__ q_s,
    const float* __restrict__ k_mv, const float* __restrict__ k_s,
    const float* __restrict__ v_mv, const float* __restrict__ v_s,
    float* __restrict__ o_mv, float* __restrict__ o_s)
{
  int q  = blockIdx.x*256 + threadIdx.x;
  int bh = blockIdx.y;
  int b = bh>>3, h = bh&7;
  size_t tq = (size_t)b*T_ + q;

  float qm[16];
  { const float4* p4=(const float4*)(q_mv + tq*128 + h*16);
    #pragma unroll
    for (int i=0;i<4;i++){ float4 v=p4[i]; qm[i*4]=v.x; qm[i*4+1]=v.y; qm[i*4+2]=v.z; qm[i*4+3]=v.w; } }
  float qs0=q_s[tq*24+h*3+0], qs1=q_s[tq*24+h*3+1], qs2=q_s[tq*24+h*3+2];

  const float scale = 0.3015113445777636f;  // 1/sqrt(11)
  float m=-1e30f, l=0.f, as0=0.f, as1=0.f, as2=0.f;
  float am[16];
  #pragma unroll
  for (int p=0;p<16;p++) am[p]=0.f;

  int kend = ((q>>4)<<4) + 16;              // exclusive; times[q] >= times[s]
  size_t brow = (size_t)b*T_;
  for (int s=0; s<kend; ++s){
    size_t ts = brow + s;
    float km[16];
    { const float4* p4=(const float4*)(k_mv + ts*128 + h*16);
      #pragma unroll
      for (int i=0;i<4;i++){ float4 v=p4[i]; km[i*4]=v.x; km[i*4+1]=v.y; km[i*4+2]=v.z; km[i*4+3]=v.w; } }
    float sc = qm[0]*km[0]+qm[2]*km[2]+qm[3]*km[3]+qm[4]*km[4]
             + qm[8]*km[8]+qm[9]*km[9]+qm[10]*km[10]+qm[14]*km[14];
    const float* ksp = k_s + ts*24 + h*3;
    sc += qs0*ksp[0]+qs1*ksp[1]+qs2*ksp[2];
    sc *= scale;
    float c;
    if (sc > m){
      float r = __expf(m - sc);
      l *= r; as0*=r; as1*=r; as2*=r;
      #pragma unroll
      for (int p=0;p<16;p++) am[p]*=r;
      m = sc; c = 1.f;
    } else {
      c = __expf(sc - m);
    }
    l += c;
    { const float4* p4=(const float4*)(v_mv + ts*128 + h*16);
      #pragma unroll
      for (int i=0;i<4;i++){ float4 v=p4[i];
        am[i*4]+=c*v.x; am[i*4+1]+=c*v.y; am[i*4+2]+=c*v.z; am[i*4+3]+=c*v.w; } }
    const float* vsp = v_s + ts*24 + h*3;
    as0 += c*vsp[0]; as1 += c*vsp[1]; as2 += c*vsp[2];
  }
  float inv = 1.f/l;
  float4* o4 = (float4*)(o_mv + tq*128 + h*16);
  #pragma unroll
  for (int i=0;i<4;i++){ float4 v; v.x=am[i*4]*inv; v.y=am[i*4+1]*inv; v.z=am[i*4+2]*inv; v.w=am[i*4+3]*inv; o4[i]=v; }
  float* osp = o_s + tq*24 + h*3;
  osp[0]=as0*inv; osp[1]=as1*inv; osp[2]=as2*inv;
}

// ---- K4: attn-out linear + residual + norm --------------------------------
__global__ void __launch_bounds__(256) k_ao(
    const float* __restrict__ o_mv, const float* __restrict__ o_s,
    const float* __restrict__ w_mv, const float* __restrict__ w_s2mv,
    const float* __restrict__ w_m2s, const float* __restrict__ w_s2s,
    const float* __restrict__ b_mv, const float* __restrict__ b_s,
    float* __restrict__ h_mv, const float* __restrict__ h_s,
    float* __restrict__ n_mv, float* __restrict__ n_s)
{
  int tt = blockIdx.x*256 + threadIdx.x;
  if (tt >= BTOK) return;
  float xm[8][16]; load_mv8(o_mv+(size_t)tt*128, xm);
  float xs[24];
  #pragma unroll
  for (int j=0;j<24;j++) xs[j]=o_s[(size_t)tt*24+j];
  size_t base=(size_t)tt*128, bs=(size_t)tt*24;
  float sq=0.f;
  #pragma unroll
  for (int o=0;o<8;o++){
    float y[16]; lin_one8(xm, w_mv+o*72, y);
    float e=b_mv[o];
    #pragma unroll
    for (int j=0;j<24;j++) e += w_s2mv[o*24+j]*xs[j];
    y[0]+=e;
    #pragma unroll
    for (int p=0;p<16;p++){
      float hf = h_mv[base+o*16+p] + y[p];
      h_mv[base+o*16+p] = hf;
      sq += FINNER[p]*hf*hf;
    }
  }
  float dmv = rsqrtf(sq*0.125f + 0.01f);
  #pragma unroll
  for (int o=0;o<8;o++)
    #pragma unroll
    for (int p=0;p<16;p++) n_mv[base+o*16+p] = h_mv[base+o*16+p]*dmv;

  float ssq=0.f; float hsf[24];
  #pragma unroll
  for (int d=0;d<24;d++){
    float a=b_s[d];
    #pragma unroll
    for (int i=0;i<8;i++) a += w_m2s[d*8+i]*xm[i][0];
    #pragma unroll
    for (int j=0;j<24;j++) a += w_s2s[d*24+j]*xs[j];
    float v = h_s[bs+d] + a; hsf[d]=v; ssq+=v*v;
  }
  float dss = rsqrtf(ssq*(1.f/24.f) + 0.01f);
  #pragma unroll
  for (int d=0;d<24;d++) n_s[bs+d]=hsf[d]*dss;
}

// ---- K5: m1 linear + geometric product / join bilinear + scalar gelu -----
// 64 threads = 4 tokens x 16 lanes. Phase1: lane=channel builds u in LDS.
// Phase2: lane=k does the 16-entry sparse GP/JOIN sums for 4 channel-slots.
__global__ void __launch_bounds__(64) k_m1(
    const float* __restrict__ n_mv, const float* __restrict__ n_s,
    const float* __restrict__ w_mv, const float* __restrict__ w_s2mv,
    const float* __restrict__ w_m2s, const float* __restrict__ w_s2s,
    const float* __restrict__ b_mv, const float* __restrict__ b_s,
    const int* __restrict__ gp_ij, const float* __restrict__ gp_s,
    const int* __restrict__ jn_ij, const float* __restrict__ jn_s,
    float* __restrict__ g_mv, float* __restrict__ g_s)
{
  __shared__ float U[4*272];   // 4 tokens, 256 floats + 16 pad each
  int tid = threadIdx.x;
  int tl = tid>>4, ln = tid&15;
  int tt = blockIdx.x*4 + tl;

  float xm[8][16]; load_mv8(n_mv+(size_t)tt*128, xm);
  float xs[24];
  #pragma unroll
  for (int j=0;j<24;j++) xs[j]=n_s[(size_t)tt*24+j];

  { // u channel = ln
    float y[16]; lin_one8(xm, w_mv+ln*72, y);
    float e=b_mv[ln];
    #pragma unroll
    for (int j=0;j<24;j++) e += w_s2mv[ln*24+j]*xs[j];
    y[0]+=e;
    float* u=&U[tl*272];
    #pragma unroll
    for (int p=0;p<16;p++) u[ln*16+p]=y[p];
  }
  { // scalar path: g_s = gelu(u_s)
    size_t bs=(size_t)tt*24;
    {
      int d=ln; float a=b_s[d];
      #pragma unroll
      for (int i=0;i<8;i++) a += w_m2s[d*8+i]*xm[i][0];
      #pragma unroll
      for (int j=0;j<24;j++) a += w_s2s[d*24+j]*xs[j];
      g_s[bs+d]=gelu_f(a);
    }
    if (ln < 8){
      int d=16+ln; float a=b_s[d];
      #pragma unroll
      for (int i=0;i<8;i++) a += w_m2s[d*8+i]*xm[i][0];
      #pragma unroll
      for (int j=0;j<24;j++) a += w_s2s[d*24+j]*xs[j];
      g_s[bs+d]=gelu_f(a);
    }
  }
  __syncthreads();
  const float* u=&U[tl*272];
  int k=ln;
  size_t gbase=(size_t)tt*128;
  #pragma unroll
  for (int c=0;c<4;c++){
    float accg=0.f, accj=0.f;
    #pragma unroll
    for (int e=0;e<16;e++){
      int eg=gp_ij[k*16+e]; float sg=gp_s[k*16+e];
      accg += sg * u[c*16+(eg&15)] * u[64+c*16+(eg>>4)];     // gl=ch c, gr=ch 4+c
      int ej=jn_ij[k*16+e]; float sj=jn_s[k*16+e];
      accj += sj * u[128+c*16+(ej&15)] * u[192+c*16+(ej>>4)]; // jl=8+c, jr=12+c
    }
    g_mv[gbase + c*16 + k]     = accg;
    g_mv[gbase + (4+c)*16 + k] = accj;
  }
}

// ---- K6: gate + m2 linear + residual + out projection + pos/vel ----------
// (scalar path after this point only feeds output comp 0 which is unused)
__global__ void __launch_bounds__(256) k_m2out(
    const float* __restrict__ g_mv, const float* __restrict__ g_s,
    const float* __restrict__ w_mv, const float* __restrict__ w_s2mv,
    const float* __restrict__ b_mv,
    const float* __restrict__ h_mv,
    const float* __restrict__ w_out_mv,
    float* __restrict__ out)
{
  int tt = blockIdx.x*256 + threadIdx.x;
  if (tt >= BTOK) return;
  float gm[8][16]; load_mv8(g_mv+(size_t)tt*128, gm);
  #pragma unroll
  for (int c=0;c<8;c++){
    float gt = gelu_f(gm[c][0]);
    #pragma unroll
    for (int p=0;p<16;p++) gm[c][p]*=gt;
  }
  float gs[24];
  #pragma unroll
  for (int j=0;j<24;j++) gs[j]=g_s[(size_t)tt*24+j];

  size_t base=(size_t)tt*128;
  float oa[16];
  #pragma unroll
  for (int p=0;p<16;p++) oa[p]=0.f;
  #pragma unroll
  for (int o=0;o<8;o++){
    float y[16]; lin_one8(gm, w_mv+o*72, y);
    float e=b_mv[o];
    #pragma unroll
    for (int j=0;j<24;j++) e += w_s2mv[o*24+j]*gs[j];
    y[0]+=e;
    float hf[16];
    #pragma unroll
    for (int p=0;p<16;p++) hf[p]=h_mv[base+o*16+p]+y[p];
    const float* wo = w_out_mv + o*9;
    #pragma unroll
    for (int p=0;p<16;p++){
      float v = wo[GRADE[p]]*hf[p];
      if (AUGK[p]>=0) v += wo[AUGK[p]]*hf[AUGS[p]];
      oa[p]+=v;
    }
  }
  float d = oa[14];
  d = (fabsf(d)>0.001f) ? d : (d>=0.f ? 0.001f : -0.001f);
  size_t ob=(size_t)tt*6;
  out[ob+0]=-oa[13]/d;
  out[ob+1]= oa[12]/d;
  out[ob+2]=-oa[11]/d;
  out[ob+3]=2.f*oa[5];
  out[ob+4]=2.f*oa[6];
  out[ob+5]=2.f*oa[7];
}

extern "C" void kernel_launch(void* const* d_in, const int* in_sizes, int n_in,
                              void* d_out, int out_size, void* d_ws, size_t ws_size,
                              hipStream_t stream)
{
  (void)in_sizes; (void)n_in; (void)out_size; (void)ws_size;
  const float* x         =(const float*)d_in[0];
  const float* w_in_mv   =(const float*)d_in[1];
  const float* b_in_mv   =(const float*)d_in[2];
  const float* w_in_m2s  =(const float*)d_in[3];
  const float* b_in_s    =(const float*)d_in[4];
  const float* w_qkv_mv  =(const float*)d_in[5];
  const float* w_qkv_s2mv=(const float*)d_in[6];
  const float* w_qkv_m2s =(const float*)d_in[7];
  const float* w_qkv_s2s =(const float*)d_in[8];
  const float* w_ao_mv   =(const float*)d_in[9];
  const float* w_ao_s2mv =(const float*)d_in[10];
  const float* w_ao_m2s  =(const float*)d_in[11];
  const float* w_ao_s2s  =(const float*)d_in[12];
  const float* b_ao_mv   =(const float*)d_in[13];
  const float* b_ao_s    =(const float*)d_in[14];
  const float* w_m1_mv   =(const float*)d_in[15];
  const float* w_m1_s2mv =(const float*)d_in[16];
  const float* w_m1_m2s  =(const float*)d_in[17];
  const float* w_m1_s2s  =(const float*)d_in[18];
  const float* b_m1_mv   =(const float*)d_in[19];
  const float* b_m1_s    =(const float*)d_in[20];
  const float* w_m2_mv   =(const float*)d_in[21];
  const float* w_m2_s2mv =(const float*)d_in[22];
  const float* b_m2_mv   =(const float*)d_in[25];
  const float* w_out_mv  =(const float*)d_in[27];
  float* outp=(float*)d_out;

  float* ws=(float*)d_ws;
  size_t off=0;
  int*   gp_ij=(int*)(ws+off); off+=256;
  float* gp_s = ws+off;        off+=256;
  int*   jn_ij=(int*)(ws+off); off+=256;
  float* jn_s = ws+off;        off+=256;
  float* h_mv = ws+off; off+=(size_t)BTOK*128;
  float* h_s  = ws+off; off+=(size_t)BTOK*24;
  float* n_mv = ws+off; off+=(size_t)BTOK*128;
  float* n_s  = ws+off; off+=(size_t)BTOK*24;
  float* q_mv = ws+off; off+=(size_t)BTOK*128;
  float* q_s  = ws+off; off+=(size_t)BTOK*24;
  float* k_mv = ws+off; off+=(size_t)BTOK*128;
  float* k_s  = ws+off; off+=(size_t)BTOK*24;
  float* v_mv = ws+off; off+=(size_t)BTOK*128;
  float* v_s  = ws+off; off+=(size_t)BTOK*24;
  float* o_mv = ws+off; off+=(size_t)BTOK*128;
  float* o_s  = ws+off; off+=(size_t)BTOK*24;
  float* g_mv = ws+off; off+=(size_t)BTOK*128;
  float* g_s  = ws+off; off+=(size_t)BTOK*24;

  build_tables_k<<<1,64,0,stream>>>(gp_ij,gp_s,jn_ij,jn_s);
  k_embed<<<BTOK/256,256,0,stream>>>(x,w_in_mv,b_in_mv,w_in_m2s,b_in_s,h_mv,h_s,n_mv,n_s);
  k_qkv  <<<BTOK/256,256,0,stream>>>(n_mv,n_s,w_qkv_mv,w_qkv_s2mv,w_qkv_m2s,w_qkv_s2s,
                                     q_mv,q_s,k_mv,k_s,v_mv,v_s);
  k_attn <<<dim3(T_/256,16),256,0,stream>>>(q_mv,q_s,k_mv,k_s,v_mv,v_s,o_mv,o_s);
  k_ao   <<<BTOK/256,256,0,stream>>>(o_mv,o_s,w_ao_mv,w_ao_s2mv,w_ao_m2s,w_ao_s2s,
                                     b_ao_mv,b_ao_s,h_mv,h_s,n_mv,n_s);
  k_m1   <<<BTOK/4,64,0,stream>>>(n_mv,n_s,w_m1_mv,w_m1_s2mv,w_m1_m2s,w_m1_s2s,
                                  b_m1_mv,b_m1_s,gp_ij,gp_s,jn_ij,jn_s,g_mv,g_s);
  k_m2out<<<BTOK/256,256,0,stream>>>(g_mv,g_s,w_m2_mv,w_m2_s2mv,b_m2_mv,h_mv,w_out_mv,outp);
}

// Round 2
// 283.208 us; speedup vs baseline: 6.2574x; 6.2574x over previous
//
#include <hip/hip_runtime.h>
#include <math.h>

#define T_    2048
#define BTOK  4096   // B * T
#define QB    32
#define KB    32

namespace {
constexpr int GRADE[16] = {0,1,1,1,1,2,2,2,2,2,2,3,3,3,3,4};
// e0-augmentation: target comp p gets w[k]*x[src]
constexpr int AUGK[16]  = {-1,5,-1,-1,-1,6,6,6,-1,-1,-1,7,7,7,-1,8};
constexpr int AUGS[16]  = { 0,0, 0, 0, 0,2,3,4, 0, 0, 0,8,9,10,0,14};
constexpr float FINNER[16] = {1.f,0.f,1.f,1.f,1.f,0.f,0.f,0.f,1.f,1.f,1.f,0.f,0.f,0.f,1.f,0.f};
}

__device__ __forceinline__ float gelu_f(float v){
  return 0.5f*v*(1.f + erff(v*0.70710678118654752f));
}

// canonical reordering sign for blade bitmasks
__device__ __forceinline__ int rsign_d(int a, int b){
  int s=0; a>>=1; while(a){ s += __popc(a&b); a>>=1; } return (s&1) ? -1 : 1;
}

// Build sparse GP and JOIN tables: per output component k, 16 padded entries
// (i | j<<4, sign). Blade order of the reference <-> bitmask maps hardcoded.
__global__ void build_tables_k(int* __restrict__ gp_ij, float* __restrict__ gp_s,
                               int* __restrict__ jn_ij, float* __restrict__ jn_s){
  const int mask_of[16]={0,1,2,4,8,3,5,9,6,10,12,7,11,13,14,15};
  const int idx_of[16] ={0,1,2,5,3,6,8,11,4,7,9,12,10,13,14,15};
  int t = threadIdx.x;
  if (t < 16){
    int k=t, km=mask_of[k], slot=0;
    for (int i=0;i<16;i++){
      int im=mask_of[i], jm=im^km;
      if (im & jm & 1) continue;              // e0 in common -> metric 0
      gp_ij[k*16+slot] = i | (idx_of[jm]<<4);
      gp_s [k*16+slot] = (float)rsign_d(im,jm);
      slot++;
    }
    for(;slot<16;slot++){ gp_ij[k*16+slot]=0; gp_s[k*16+slot]=0.f; }
  } else if (t < 32){
    int p=t-16, pm=mask_of[p], rest=15&~pm, slot=0;
    for (int u=0;u<16;u++){
      if (u & ~rest) continue;
      int am = pm|u, bm = pm|(rest&~u);       // a&b=pm, a|b=1111
      float s = (float)( rsign_d(pm,15&~pm) * rsign_d(15&~am,15&~bm)
                       * rsign_d(am,15&~am) * rsign_d(bm,15&~bm) );
      jn_ij[p*16+slot] = idx_of[am] | (idx_of[bm]<<4);
      jn_s [p*16+slot] = s;
      slot++;
    }
    for(;slot<16;slot++){ jn_ij[p*16+slot]=0; jn_s[p*16+slot]=0.f; }
  }
}

__device__ __forceinline__ void load_mv8(const float* __restrict__ g, float x[8][16]){
  const float4* g4 = (const float4*)g;
  #pragma unroll
  for (int i=0;i<32;i++){
    float4 v = g4[i];
    x[i>>2][(i&3)*4+0]=v.x; x[i>>2][(i&3)*4+1]=v.y;
    x[i>>2][(i&3)*4+2]=v.z; x[i>>2][(i&3)*4+3]=v.w;
  }
}

// one output channel of equi_linear (mv part), I=8 input channels, w = 8x9 slice
__device__ __forceinline__ void lin_one8(const float x[8][16], const float* __restrict__ w, float y[16]){
  #pragma unroll
  for (int p=0;p<16;p++) y[p]=0.f;
  #pragma unroll
  for (int i=0;i<8;i++){
    const float* wi = w + i*9;
    #pragma unroll
    for (int p=0;p<16;p++){
      float v = wi[GRADE[p]]*x[i][p];
      if (AUGK[p]>=0) v += wi[AUGK[p]]*x[i][AUGS[p]];
      y[p] += v;
    }
  }
}

// ---- K1: embed + input linear + norm -------------------------------------
__global__ void __launch_bounds__(256) k_embed(
    const float* __restrict__ x,
    const float* __restrict__ w_in_mv, const float* __restrict__ b_in_mv,
    const float* __restrict__ w_in_m2s, const float* __restrict__ b_in_s,
    float* __restrict__ h_mv, float* __restrict__ h_s,
    float* __restrict__ n_mv, float* __restrict__ n_s)
{
  int tt = blockIdx.x*256 + threadIdx.x;
  if (tt >= BTOK) return;
  const float* xp = x + (size_t)tt*6;
  float mv[16];
  #pragma unroll
  for (int p=0;p<16;p++) mv[p]=0.f;
  mv[0]=1.f; mv[14]=1.f;
  mv[13]=-xp[0]; mv[12]=xp[1]; mv[11]=-xp[2];
  mv[5]=0.5f*xp[3]; mv[6]=0.5f*xp[4]; mv[7]=0.5f*xp[5];

  float hm[8][16]; float sq=0.f;
  #pragma unroll
  for (int o=0;o<8;o++){
    const float* wo = w_in_mv + o*9;
    #pragma unroll
    for (int p=0;p<16;p++){
      float v = wo[GRADE[p]]*mv[p];
      if (AUGK[p]>=0) v += wo[AUGK[p]]*mv[AUGS[p]];
      if (p==0) v += b_in_mv[o];
      hm[o][p]=v; sq += FINNER[p]*v*v;
    }
  }
  float dmv = rsqrtf(sq*0.125f + 0.01f);
  float hs[24]; float ssq=0.f;
  #pragma unroll
  for (int j=0;j<24;j++){ float v = w_in_m2s[j] + b_in_s[j]; hs[j]=v; ssq+=v*v; }
  float dss = rsqrtf(ssq*(1.f/24.f) + 0.01f);

  size_t base=(size_t)tt*128, bs=(size_t)tt*24;
  #pragma unroll
  for (int o=0;o<8;o++)
    #pragma unroll
    for (int p=0;p<16;p++){ h_mv[base+o*16+p]=hm[o][p]; n_mv[base+o*16+p]=hm[o][p]*dmv; }
  #pragma unroll
  for (int j=0;j<24;j++){ h_s[bs+j]=hs[j]; n_s[bs+j]=hs[j]*dss; }
}

// ---- K2: QKV projections, packed per-head layouts ------------------------
// q/k pack: [bh][t][12] = 8 INNER comps {0,2,3,4,8,9,10,14} + 3 scalars + pad
//           (q pre-multiplied by softmax scale)
// v pack:   [bh][t][20] = 16 comps + 3 scalars + pad
__global__ void __launch_bounds__(256) k_qkv(
    const float* __restrict__ n_mv, const float* __restrict__ n_s,
    const float* __restrict__ w_mv, const float* __restrict__ w_s2mv,
    const float* __restrict__ w_m2s, const float* __restrict__ w_s2s,
    float* __restrict__ qp_, float* __restrict__ kp_, float* __restrict__ vp_)
{
  int pr = blockIdx.y;             // 0=q 1=k 2=v
  int tt = blockIdx.x*256 + threadIdx.x;
  if (tt >= BTOK) return;
  int b = tt >> 11, t = tt & (T_-1);
  float xm[8][16]; load_mv8(n_mv+(size_t)tt*128, xm);
  float xs[24];
  #pragma unroll
  for (int j=0;j<24;j++) xs[j]=n_s[(size_t)tt*24+j];

  const float* wmv   = w_mv   + pr*576;
  const float* ws2mv = w_s2mv + pr*192;
  const float* wm2s  = w_m2s  + pr*192;
  const float* ws2s  = w_s2s  + pr*576;

  float sval[24];
  #pragma unroll
  for (int d=0;d<24;d++){
    float a=0.f;
    #pragma unroll
    for (int i=0;i<8;i++) a += wm2s[d*8+i]*xm[i][0];
    #pragma unroll
    for (int j=0;j<24;j++) a += ws2s[d*24+j]*xs[j];
    sval[d]=a;
  }

  const float scale = 0.3015113445777636f;  // 1/sqrt(11)
  #pragma unroll
  for (int o=0;o<8;o++){
    float y[16]; lin_one8(xm, wmv+o*72, y);
    float e=0.f;
    #pragma unroll
    for (int j=0;j<24;j++) e += ws2mv[o*24+j]*xs[j];
    y[0]+=e;
    size_t rb = ((size_t)(b*8+o)*T_ + t);
    if (pr==2){
      float* vr = vp_ + rb*20;
      #pragma unroll
      for (int p=0;p<16;p++) vr[p]=y[p];
      vr[16]=sval[o*3]; vr[17]=sval[o*3+1]; vr[18]=sval[o*3+2]; vr[19]=0.f;
    } else {
      float* r = (pr==0? qp_:kp_) + rb*12;
      float f = (pr==0)? scale : 1.f;
      r[0]=y[0]*f;  r[1]=y[2]*f;  r[2]=y[3]*f;  r[3]=y[4]*f;
      r[4]=y[8]*f;  r[5]=y[9]*f;  r[6]=y[10]*f; r[7]=y[14]*f;
      r[8]=sval[o*3]*f; r[9]=sval[o*3+1]*f; r[10]=sval[o*3+2]*f; r[11]=0.f;
    }
  }
}

// ---- K3: block-causal attention ------------------------------------------
// block = 256 thr = 32 queries x 8 key-lanes, one (b,h). K/V tiles in LDS.
__global__ void __launch_bounds__(256) k_attn(
    const float* __restrict__ qp_, const float* __restrict__ kp_,
    const float* __restrict__ vp_,
    float* __restrict__ o_mv, float* __restrict__ o_s)
{
  __shared__ float Kt[KB*12];
  __shared__ float Vt[KB*20];
  int tid = threadIdx.x;
  int qi = tid>>3, ki = tid&7;
  int bh = blockIdx.y; int b = bh>>3, h = bh&7;
  int q0 = blockIdx.x*QB;
  int q  = q0 + qi;

  float qp[12];
  { const float4* p4 = (const float4*)(qp_ + ((size_t)bh*T_ + q)*12);
    #pragma unroll
    for (int i=0;i<3;i++){ float4 v=p4[i]; qp[i*4]=v.x; qp[i*4+1]=v.y; qp[i*4+2]=v.z; qp[i*4+3]=v.w; } }

  int kend_q = (q & ~15) + 16;
  int kend_b = q0 + QB;
  float m=-1e30f, l=0.f, as0=0.f, as1=0.f, as2=0.f;
  float am[16];
  #pragma unroll
  for (int p=0;p<16;p++) am[p]=0.f;

  const float4* gk = (const float4*)(kp_ + (size_t)bh*T_*12);
  const float4* gv = (const float4*)(vp_ + (size_t)bh*T_*20);

  for (int s0=0; s0<kend_b; s0+=KB){
    // stage KB keys: K = KB*3 float4 (96), V = KB*5 float4 (160); 256 total
    if (tid < 96) ((float4*)Kt)[tid] = gk[s0*3 + tid];
    else          ((float4*)Vt)[tid-96] = gv[s0*5 + (tid-96)];
    __syncthreads();
    int smax = min(KB, kend_q - s0);
    for (int r = ki; r < smax; r += 8){
      const float4* K4 = (const float4*)&Kt[r*12];
      float4 k0=K4[0], k1=K4[1], k2=K4[2];
      float sA = qp[0]*k0.x + qp[1]*k0.y + qp[2]*k0.z + qp[3]*k0.w;
      float sB = qp[4]*k1.x + qp[5]*k1.y + qp[6]*k1.z + qp[7]*k1.w;
      float sC = qp[8]*k2.x + qp[9]*k2.y + qp[10]*k2.z;
      float sc = sA + (sB + sC);
      float mn = fmaxf(m, sc);
      float ea = __expf(m - mn);
      float c  = __expf(sc - mn);
      const float4* V4 = (const float4*)&Vt[r*20];
      float4 v0=V4[0], v1=V4[1], v2=V4[2], v3=V4[3], v4=V4[4];
      l = l*ea + c;
      am[0] = am[0] *ea + c*v0.x; am[1] = am[1] *ea + c*v0.y;
      am[2] = am[2] *ea + c*v0.z; am[3] = am[3] *ea + c*v0.w;
      am[4] = am[4] *ea + c*v1.x; am[5] = am[5] *ea + c*v1.y;
      am[6] = am[6] *ea + c*v1.z; am[7] = am[7] *ea + c*v1.w;
      am[8] = am[8] *ea + c*v2.x; am[9] = am[9] *ea + c*v2.y;
      am[10]= am[10]*ea + c*v2.z; am[11]= am[11]*ea + c*v2.w;
      am[12]= am[12]*ea + c*v3.x; am[13]= am[13]*ea + c*v3.y;
      am[14]= am[14]*ea + c*v3.z; am[15]= am[15]*ea + c*v3.w;
      as0 = as0*ea + c*v4.x; as1 = as1*ea + c*v4.y; as2 = as2*ea + c*v4.z;
      m = mn;
    }
    __syncthreads();
  }

  // butterfly merge across the 8 key-lanes (lanes tid&7 within wave)
  #pragma unroll
  for (int mask=1; mask<8; mask<<=1){
    float om=__shfl_xor(m,mask), ol=__shfl_xor(l,mask);
    float oa[16];
    #pragma unroll
    for (int p=0;p<16;p++) oa[p]=__shfl_xor(am[p],mask);
    float o0=__shfl_xor(as0,mask), o1=__shfl_xor(as1,mask), o2=__shfl_xor(as2,mask);
    float mn=fmaxf(m,om);
    float a=__expf(m-mn), bb=__expf(om-mn);
    l=l*a+ol*bb;
    #pragma unroll
    for (int p=0;p<16;p++) am[p]=am[p]*a+oa[p]*bb;
    as0=as0*a+o0*bb; as1=as1*a+o1*bb; as2=as2*a+o2*bb;
    m=mn;
  }

  if (ki==0){
    float inv=1.f/l;
    size_t tq=(size_t)b*T_+q;
    float4* o4=(float4*)(o_mv+tq*128+h*16);
    #pragma unroll
    for (int i=0;i<4;i++){ float4 v; v.x=am[i*4]*inv; v.y=am[i*4+1]*inv; v.z=am[i*4+2]*inv; v.w=am[i*4+3]*inv; o4[i]=v; }
    float* osp=o_s+tq*24+h*3;
    osp[0]=as0*inv; osp[1]=as1*inv; osp[2]=as2*inv;
  }
}

// ---- K4: attn-out linear + residual + norm --------------------------------
__global__ void __launch_bounds__(256) k_ao(
    const float* __restrict__ o_mv, const float* __restrict__ o_s,
    const float* __restrict__ w_mv, const float* __restrict__ w_s2mv,
    const float* __restrict__ w_m2s, const float* __restrict__ w_s2s,
    const float* __restrict__ b_mv, const float* __restrict__ b_s,
    float* __restrict__ h_mv, const float* __restrict__ h_s,
    float* __restrict__ n_mv, float* __restrict__ n_s)
{
  int tt = blockIdx.x*256 + threadIdx.x;
  if (tt >= BTOK) return;
  float xm[8][16]; load_mv8(o_mv+(size_t)tt*128, xm);
  float xs[24];
  #pragma unroll
  for (int j=0;j<24;j++) xs[j]=o_s[(size_t)tt*24+j];
  size_t base=(size_t)tt*128, bs=(size_t)tt*24;
  float sq=0.f;
  #pragma unroll
  for (int o=0;o<8;o++){
    float y[16]; lin_one8(xm, w_mv+o*72, y);
    float e=b_mv[o];
    #pragma unroll
    for (int j=0;j<24;j++) e += w_s2mv[o*24+j]*xs[j];
    y[0]+=e;
    #pragma unroll
    for (int p=0;p<16;p++){
      float hf = h_mv[base+o*16+p] + y[p];
      h_mv[base+o*16+p] = hf;
      sq += FINNER[p]*hf*hf;
    }
  }
  float dmv = rsqrtf(sq*0.125f + 0.01f);
  #pragma unroll
  for (int o=0;o<8;o++)
    #pragma unroll
    for (int p=0;p<16;p++) n_mv[base+o*16+p] = h_mv[base+o*16+p]*dmv;

  float ssq=0.f; float hsf[24];
  #pragma unroll
  for (int d=0;d<24;d++){
    float a=b_s[d];
    #pragma unroll
    for (int i=0;i<8;i++) a += w_m2s[d*8+i]*xm[i][0];
    #pragma unroll
    for (int j=0;j<24;j++) a += w_s2s[d*24+j]*xs[j];
    float v = h_s[bs+d] + a; hsf[d]=v; ssq+=v*v;
  }
  float dss = rsqrtf(ssq*(1.f/24.f) + 0.01f);
  #pragma unroll
  for (int d=0;d<24;d++) n_s[bs+d]=hsf[d]*dss;
}

// ---- K5: m1 linear + geometric product / join bilinear + scalar gelu -----
__global__ void __launch_bounds__(64) k_m1(
    const float* __restrict__ n_mv, const float* __restrict__ n_s,
    const float* __restrict__ w_mv, const float* __restrict__ w_s2mv,
    const float* __restrict__ w_m2s, const float* __restrict__ w_s2s,
    const float* __restrict__ b_mv, const float* __restrict__ b_s,
    const int* __restrict__ gp_ij, const float* __restrict__ gp_s,
    const int* __restrict__ jn_ij, const float* __restrict__ jn_s,
    float* __restrict__ g_mv, float* __restrict__ g_s)
{
  __shared__ float U[4*272];   // 4 tokens, 256 floats + 16 pad each
  int tid = threadIdx.x;
  int tl = tid>>4, ln = tid&15;
  int tt = blockIdx.x*4 + tl;

  float xm[8][16]; load_mv8(n_mv+(size_t)tt*128, xm);
  float xs[24];
  #pragma unroll
  for (int j=0;j<24;j++) xs[j]=n_s[(size_t)tt*24+j];

  { // u channel = ln
    float y[16]; lin_one8(xm, w_mv+ln*72, y);
    float e=b_mv[ln];
    #pragma unroll
    for (int j=0;j<24;j++) e += w_s2mv[ln*24+j]*xs[j];
    y[0]+=e;
    float* u=&U[tl*272];
    #pragma unroll
    for (int p=0;p<16;p++) u[ln*16+p]=y[p];
  }
  { // scalar path: g_s = gelu(u_s)
    size_t bs=(size_t)tt*24;
    {
      int d=ln; float a=b_s[d];
      #pragma unroll
      for (int i=0;i<8;i++) a += w_m2s[d*8+i]*xm[i][0];
      #pragma unroll
      for (int j=0;j<24;j++) a += w_s2s[d*24+j]*xs[j];
      g_s[bs+d]=gelu_f(a);
    }
    if (ln < 8){
      int d=16+ln; float a=b_s[d];
      #pragma unroll
      for (int i=0;i<8;i++) a += w_m2s[d*8+i]*xm[i][0];
      #pragma unroll
      for (int j=0;j<24;j++) a += w_s2s[d*24+j]*xs[j];
      g_s[bs+d]=gelu_f(a);
    }
  }
  __syncthreads();
  const float* u=&U[tl*272];
  int k=ln;
  size_t gbase=(size_t)tt*128;
  #pragma unroll
  for (int c=0;c<4;c++){
    float accg=0.f, accj=0.f;
    #pragma unroll
    for (int e=0;e<16;e++){
      int eg=gp_ij[k*16+e]; float sg=gp_s[k*16+e];
      accg += sg * u[c*16+(eg&15)] * u[64+c*16+(eg>>4)];     // gl=ch c, gr=ch 4+c
      int ej=jn_ij[k*16+e]; float sj=jn_s[k*16+e];
      accj += sj * u[128+c*16+(ej&15)] * u[192+c*16+(ej>>4)]; // jl=8+c, jr=12+c
    }
    g_mv[gbase + c*16 + k]     = accg;
    g_mv[gbase + (4+c)*16 + k] = accj;
  }
}

// ---- K6: gate + m2 linear + residual + out projection + pos/vel ----------
__global__ void __launch_bounds__(256) k_m2out(
    const float* __restrict__ g_mv, const float* __restrict__ g_s,
    const float* __restrict__ w_mv, const float* __restrict__ w_s2mv,
    const float* __restrict__ b_mv,
    const float* __restrict__ h_mv,
    const float* __restrict__ w_out_mv,
    float* __restrict__ out)
{
  int tt = blockIdx.x*256 + threadIdx.x;
  if (tt >= BTOK) return;
  float gm[8][16]; load_mv8(g_mv+(size_t)tt*128, gm);
  #pragma unroll
  for (int c=0;c<8;c++){
    float gt = gelu_f(gm[c][0]);
    #pragma unroll
    for (int p=0;p<16;p++) gm[c][p]*=gt;
  }
  float gs[24];
  #pragma unroll
  for (int j=0;j<24;j++) gs[j]=g_s[(size_t)tt*24+j];

  size_t base=(size_t)tt*128;
  float oa[16];
  #pragma unroll
  for (int p=0;p<16;p++) oa[p]=0.f;
  #pragma unroll
  for (int o=0;o<8;o++){
    float y[16]; lin_one8(gm, w_mv+o*72, y);
    float e=b_mv[o];
    #pragma unroll
    for (int j=0;j<24;j++) e += w_s2mv[o*24+j]*gs[j];
    y[0]+=e;
    float hf[16];
    #pragma unroll
    for (int p=0;p<16;p++) hf[p]=h_mv[base+o*16+p]+y[p];
    const float* wo = w_out_mv + o*9;
    #pragma unroll
    for (int p=0;p<16;p++){
      float v = wo[GRADE[p]]*hf[p];
      if (AUGK[p]>=0) v += wo[AUGK[p]]*hf[AUGS[p]];
      oa[p]+=v;
    }
  }
  float d = oa[14];
  d = (fabsf(d)>0.001f) ? d : (d>=0.f ? 0.001f : -0.001f);
  size_t ob=(size_t)tt*6;
  out[ob+0]=-oa[13]/d;
  out[ob+1]= oa[12]/d;
  out[ob+2]=-oa[11]/d;
  out[ob+3]=2.f*oa[5];
  out[ob+4]=2.f*oa[6];
  out[ob+5]=2.f*oa[7];
}

extern "C" void kernel_launch(void* const* d_in, const int* in_sizes, int n_in,
                              void* d_out, int out_size, void* d_ws, size_t ws_size,
                              hipStream_t stream)
{
  (void)in_sizes; (void)n_in; (void)out_size; (void)ws_size;
  const float* x         =(const float*)d_in[0];
  const float* w_in_mv   =(const float*)d_in[1];
  const float* b_in_mv   =(const float*)d_in[2];
  const float* w_in_m2s  =(const float*)d_in[3];
  const float* b_in_s    =(const float*)d_in[4];
  const float* w_qkv_mv  =(const float*)d_in[5];
  const float* w_qkv_s2mv=(const float*)d_in[6];
  const float* w_qkv_m2s =(const float*)d_in[7];
  const float* w_qkv_s2s =(const float*)d_in[8];
  const float* w_ao_mv   =(const float*)d_in[9];
  const float* w_ao_s2mv =(const float*)d_in[10];
  const float* w_ao_m2s  =(const float*)d_in[11];
  const float* w_ao_s2s  =(const float*)d_in[12];
  const float* b_ao_mv   =(const float*)d_in[13];
  const float* b_ao_s    =(const float*)d_in[14];
  const float* w_m1_mv   =(const float*)d_in[15];
  const float* w_m1_s2mv =(const float*)d_in[16];
  const float* w_m1_m2s  =(const float*)d_in[17];
  const float* w_m1_s2s  =(const float*)d_in[18];
  const float* b_m1_mv   =(const float*)d_in[19];
  const float* b_m1_s    =(const float*)d_in[20];
  const float* w_m2_mv   =(const float*)d_in[21];
  const float* w_m2_s2mv =(const float*)d_in[22];
  const float* b_m2_mv   =(const float*)d_in[25];
  const float* w_out_mv  =(const float*)d_in[27];
  float* outp=(float*)d_out;

  float* ws=(float*)d_ws;
  size_t off=0;
  int*   gp_ij=(int*)(ws+off); off+=256;
  float* gp_s = ws+off;        off+=256;
  int*   jn_ij=(int*)(ws+off); off+=256;
  float* jn_s = ws+off;        off+=256;
  float* h_mv = ws+off; off+=(size_t)BTOK*128;
  float* h_s  = ws+off; off+=(size_t)BTOK*24;
  float* n_mv = ws+off; off+=(size_t)BTOK*128;
  float* n_s  = ws+off; off+=(size_t)BTOK*24;
  float* o_mv = ws+off; off+=(size_t)BTOK*128;
  float* o_s  = ws+off; off+=(size_t)BTOK*24;
  float* g_mv = ws+off; off+=(size_t)BTOK*128;
  float* g_s  = ws+off; off+=(size_t)BTOK*24;
  float* qpk  = ws+off; off+=(size_t)16*T_*12;
  float* kpk  = ws+off; off+=(size_t)16*T_*12;
  float* vpk  = ws+off; off+=(size_t)16*T_*20;

  build_tables_k<<<1,64,0,stream>>>(gp_ij,gp_s,jn_ij,jn_s);
  k_embed<<<BTOK/256,256,0,stream>>>(x,w_in_mv,b_in_mv,w_in_m2s,b_in_s,h_mv,h_s,n_mv,n_s);
  k_qkv  <<<dim3(BTOK/256,3),256,0,stream>>>(n_mv,n_s,w_qkv_mv,w_qkv_s2mv,w_qkv_m2s,w_qkv_s2s,
                                             qpk,kpk,vpk);
  k_attn <<<dim3(T_/QB,16),256,0,stream>>>(qpk,kpk,vpk,o_mv,o_s);
  k_ao   <<<BTOK/256,256,0,stream>>>(o_mv,o_s,w_ao_mv,w_ao_s2mv,w_ao_m2s,w_ao_s2s,
                                     b_ao_mv,b_ao_s,h_mv,h_s,n_mv,n_s);
  k_m1   <<<BTOK/4,64,0,stream>>>(n_mv,n_s,w_m1_mv,w_m1_s2mv,w_m1_m2s,w_m1_s2s,
                                  b_m1_mv,b_m1_s,gp_ij,gp_s,jn_ij,jn_s,g_mv,g_s);
  k_m2out<<<BTOK/256,256,0,stream>>>(g_mv,g_s,w_m2_mv,w_m2_s2mv,b_m2_mv,h_mv,w_out_mv,outp);
}

// Round 3
// 165.412 us; speedup vs baseline: 10.7135x; 1.7121x over previous
//
#include <hip/hip_runtime.h>
#include <math.h>

#define T_    2048
#define BTOK  4096   // B * T
#define KB    64

namespace {
constexpr int GRADE[16] = {0,1,1,1,1,2,2,2,2,2,2,3,3,3,3,4};
constexpr int AUGK[16]  = {-1,5,-1,-1,-1,6,6,6,-1,-1,-1,7,7,7,-1,8};
constexpr int AUGS[16]  = { 0,0, 0, 0, 0,2,3,4, 0, 0, 0,8,9,10,0,14};
constexpr float FINNER[16] = {1.f,0.f,1.f,1.f,1.f,0.f,0.f,0.f,1.f,1.f,1.f,0.f,0.f,0.f,1.f,0.f};
}

__device__ __forceinline__ float gelu_f(float v){
  return 0.5f*v*(1.f + erff(v*0.70710678118654752f));
}

__device__ __forceinline__ int rsign_d(int a, int b){
  int s=0; a>>=1; while(a){ s += __popc(a&b); a>>=1; } return (s&1) ? -1 : 1;
}

__device__ __forceinline__ void load_mv8(const float* __restrict__ g, float x[8][16]){
  const float4* g4 = (const float4*)g;
  #pragma unroll
  for (int i=0;i<32;i++){
    float4 v = g4[i];
    x[i>>2][(i&3)*4+0]=v.x; x[i>>2][(i&3)*4+1]=v.y;
    x[i>>2][(i&3)*4+2]=v.z; x[i>>2][(i&3)*4+3]=v.w;
  }
}

__device__ __forceinline__ void lin_one8(const float x[8][16], const float* __restrict__ w, float y[16]){
  #pragma unroll
  for (int p=0;p<16;p++) y[p]=0.f;
  #pragma unroll
  for (int i=0;i<8;i++){
    const float* wi = w + i*9;
    #pragma unroll
    for (int p=0;p<16;p++){
      float v = wi[GRADE[p]]*x[i][p];
      if (AUGK[p]>=0) v += wi[AUGK[p]]*x[i][AUGS[p]];
      y[p] += v;
    }
  }
}

// ---- K_A: embed + in-linear + norm + QKV projections + pack --------------
// 64 threads = 8 tokens x 8 channel-lanes. Wave-level norm via shfl.
__global__ void __launch_bounds__(64) k_in(
    const float* __restrict__ x,
    const float* __restrict__ w_in_mv, const float* __restrict__ b_in_mv,
    const float* __restrict__ w_in_m2s, const float* __restrict__ b_in_s,
    const float* __restrict__ w_mv, const float* __restrict__ w_s2mv,
    const float* __restrict__ w_m2s, const float* __restrict__ w_s2s,
    float* __restrict__ h_mv, float* __restrict__ h_s,
    float* __restrict__ qp_, float* __restrict__ kp_, float* __restrict__ vp_)
{
  __shared__ float NS[8*168];   // per token: n_mv 128 + n_s 24 + pad
  int tid=threadIdx.x, tl=tid>>3, o=tid&7;
  int tt=blockIdx.x*8+tl;
  int b=tt>>11, t=tt&(T_-1);
  const float* xp = x+(size_t)tt*6;
  float mv[16];
  #pragma unroll
  for(int p=0;p<16;p++) mv[p]=0.f;
  mv[0]=1.f; mv[14]=1.f;
  mv[13]=-xp[0]; mv[12]=xp[1]; mv[11]=-xp[2];
  mv[5]=0.5f*xp[3]; mv[6]=0.5f*xp[4]; mv[7]=0.5f*xp[5];

  const float* wo=w_in_mv+o*9;
  float h[16]; float sq=0.f;
  #pragma unroll
  for(int p=0;p<16;p++){
    float v=wo[GRADE[p]]*mv[p];
    if(AUGK[p]>=0) v+=wo[AUGK[p]]*mv[AUGS[p]];
    if(p==0) v+=b_in_mv[o];
    h[p]=v; sq+=FINNER[p]*v*v;
  }
  sq+=__shfl_xor(sq,1); sq+=__shfl_xor(sq,2); sq+=__shfl_xor(sq,4);
  float dmv=rsqrtf(sq*0.125f+0.01f);
  float hs[3]; float ssq=0.f;
  #pragma unroll
  for(int jj=0;jj<3;jj++){ float v=w_in_m2s[o*3+jj]+b_in_s[o*3+jj]; hs[jj]=v; ssq+=v*v; }
  ssq+=__shfl_xor(ssq,1); ssq+=__shfl_xor(ssq,2); ssq+=__shfl_xor(ssq,4);
  float dss=rsqrtf(ssq*(1.f/24.f)+0.01f);

  { float4* hg=(float4*)(h_mv+(size_t)tt*128+o*16);
    hg[0]=make_float4(h[0],h[1],h[2],h[3]);
    hg[1]=make_float4(h[4],h[5],h[6],h[7]);
    hg[2]=make_float4(h[8],h[9],h[10],h[11]);
    hg[3]=make_float4(h[12],h[13],h[14],h[15]); }
  #pragma unroll
  for(int jj=0;jj<3;jj++) h_s[(size_t)tt*24+o*3+jj]=hs[jj];

  float* ns=&NS[tl*168];
  #pragma unroll
  for(int p=0;p<16;p++) ns[o*16+p]=h[p]*dmv;
  #pragma unroll
  for(int jj=0;jj<3;jj++) ns[128+o*3+jj]=hs[jj]*dss;
  __syncthreads();

  // three projections, output channel o of each
  float yq[16],yk[16],yv[16];
  #pragma unroll
  for(int p=0;p<16;p++){ yq[p]=0.f; yk[p]=0.f; yv[p]=0.f; }
  float nx0[8];
  const float* wq=w_mv+o*72;
  for(int i=0;i<8;i++){
    float xi[16];
    const float4* xs4=(const float4*)&ns[i*16];
    #pragma unroll
    for(int r4=0;r4<4;r4++){ float4 v=xs4[r4]; xi[r4*4]=v.x; xi[r4*4+1]=v.y; xi[r4*4+2]=v.z; xi[r4*4+3]=v.w; }
    nx0[i]=xi[0];
    const float* aq=wq+i*9; const float* ak=aq+576; const float* av=aq+1152;
    #pragma unroll
    for(int p=0;p<16;p++){
      float bb=xi[p];
      yq[p]+=aq[GRADE[p]]*bb; yk[p]+=ak[GRADE[p]]*bb; yv[p]+=av[GRADE[p]]*bb;
      if(AUGK[p]>=0){
        float au=xi[AUGS[p]];
        yq[p]+=aq[AUGK[p]]*au; yk[p]+=ak[AUGK[p]]*au; yv[p]+=av[AUGK[p]]*au;
      }
    }
  }
  float eq=0.f,ek=0.f,ev=0.f;
  float sq3[3]={0,0,0}, sk3[3]={0,0,0}, sv3[3]={0,0,0};
  const float* s2mv_q=w_s2mv+o*24;
  for(int j=0;j<24;j++){
    float s=ns[128+j];
    eq+=s2mv_q[j]*s; ek+=s2mv_q[192+j]*s; ev+=s2mv_q[384+j]*s;
    #pragma unroll
    for(int jj=0;jj<3;jj++){
      int d=o*3+jj;
      sq3[jj]+=w_s2s[d*24+j]*s;
      sk3[jj]+=w_s2s[576+d*24+j]*s;
      sv3[jj]+=w_s2s[1152+d*24+j]*s;
    }
  }
  for(int i=0;i<8;i++){
    #pragma unroll
    for(int jj=0;jj<3;jj++){
      int d=o*3+jj;
      sq3[jj]+=w_m2s[d*8+i]*nx0[i];
      sk3[jj]+=w_m2s[192+d*8+i]*nx0[i];
      sv3[jj]+=w_m2s[384+d*8+i]*nx0[i];
    }
  }
  yq[0]+=eq; yk[0]+=ek; yv[0]+=ev;

  const float scale = 0.3015113445777636f;  // 1/sqrt(11)
  size_t rb=((size_t)(b*8+o)*T_+t);
  float4* qr=(float4*)(qp_+rb*12);
  qr[0]=make_float4(yq[0]*scale, yq[2]*scale, yq[3]*scale, yq[4]*scale);
  qr[1]=make_float4(yq[8]*scale, yq[9]*scale, yq[10]*scale, yq[14]*scale);
  qr[2]=make_float4(sq3[0]*scale, sq3[1]*scale, sq3[2]*scale, 0.f);
  float4* kr=(float4*)(kp_+rb*12);
  kr[0]=make_float4(yk[0],yk[2],yk[3],yk[4]);
  kr[1]=make_float4(yk[8],yk[9],yk[10],yk[14]);
  kr[2]=make_float4(sk3[0],sk3[1],sk3[2],0.f);
  float4* vr=(float4*)(vp_+rb*20);
  vr[0]=make_float4(yv[0],yv[1],yv[2],yv[3]);
  vr[1]=make_float4(yv[4],yv[5],yv[6],yv[7]);
  vr[2]=make_float4(yv[8],yv[9],yv[10],yv[11]);
  vr[3]=make_float4(yv[12],yv[13],yv[14],yv[15]);
  vr[4]=make_float4(sv3[0],sv3[1],sv3[2],0.f);
}

// ---- K_B: attention. 256 thr = 32 q-threads x 8 key-lanes, 2 queries/thread.
__global__ void __launch_bounds__(256) k_attn(
    const float* __restrict__ qp_, const float* __restrict__ kp_,
    const float* __restrict__ vp_,
    float* __restrict__ o_mv, float* __restrict__ o_s)
{
  __shared__ float Kt[KB*12];
  __shared__ float Vt[KB*20];
  int tid=threadIdx.x; int qi=tid>>3, ki=tid&7;
  int j=blockIdx.x;
  int bh = j & 15;
  int qs = (j < 256) ? (31 - (j>>4)) : ((j-256)>>4);   // work-paired ordering
  int b=bh>>3, h=bh&7;
  int q0=qs*64;
  int qA=q0+qi, qB=q0+32+qi;

  float qpA[12], qpB[12];
  { const float4* p4=(const float4*)(qp_+((size_t)bh*T_+qA)*12);
    #pragma unroll
    for(int i=0;i<3;i++){ float4 v=p4[i]; qpA[i*4]=v.x; qpA[i*4+1]=v.y; qpA[i*4+2]=v.z; qpA[i*4+3]=v.w; } }
  { const float4* p4=(const float4*)(qp_+((size_t)bh*T_+qB)*12);
    #pragma unroll
    for(int i=0;i<3;i++){ float4 v=p4[i]; qpB[i*4]=v.x; qpB[i*4+1]=v.y; qpB[i*4+2]=v.z; qpB[i*4+3]=v.w; } }

  int kendA=(qA&~15)+16, kendB=(qB&~15)+16;
  float mA=-1e30f,lA=0.f, mB=-1e30f,lB=0.f;
  float amA[16], amB[16];
  #pragma unroll
  for(int p=0;p<16;p++){ amA[p]=0.f; amB[p]=0.f; }
  float asA0=0.f,asA1=0.f,asA2=0.f, asB0=0.f,asB1=0.f,asB2=0.f;

  const float4* gk=(const float4*)(kp_+(size_t)bh*T_*12);
  const float4* gv=(const float4*)(vp_+(size_t)bh*T_*20);

  for(int s0=0; s0<q0+64; s0+=KB){
    int i1=tid, i2=tid+256;
    if(i1<192) ((float4*)Kt)[i1]=gk[s0*3+i1];
    else       ((float4*)Vt)[i1-192]=gv[s0*5+(i1-192)];
    ((float4*)Vt)[i2-192]=gv[s0*5+(i2-192)];
    __syncthreads();
    #pragma unroll
    for(int g=0; g<2; ++g){
      int rb=ki+g*32;
      float sA[4], sB[4];
      #pragma unroll
      for(int u=0;u<4;u++){
        int r=rb+u*8;
        const float4* K4=(const float4*)&Kt[r*12];
        float4 k0=K4[0],k1=K4[1],k2=K4[2];
        float dA = qpA[0]*k0.x+qpA[1]*k0.y+qpA[2]*k0.z+qpA[3]*k0.w
                 + qpA[4]*k1.x+qpA[5]*k1.y+qpA[6]*k1.z+qpA[7]*k1.w
                 + qpA[8]*k2.x+qpA[9]*k2.y+qpA[10]*k2.z;
        float dB = qpB[0]*k0.x+qpB[1]*k0.y+qpB[2]*k0.z+qpB[3]*k0.w
                 + qpB[4]*k1.x+qpB[5]*k1.y+qpB[6]*k1.z+qpB[7]*k1.w
                 + qpB[8]*k2.x+qpB[9]*k2.y+qpB[10]*k2.z;
        int s=s0+r;
        sA[u]=(s<kendA)? dA : -1e30f;
        sB[u]=(s<kendB)? dB : -1e30f;
      }
      float tmA=fmaxf(fmaxf(sA[0],sA[1]),fmaxf(sA[2],sA[3]));
      float tmB=fmaxf(fmaxf(sB[0],sB[1]),fmaxf(sB[2],sB[3]));
      float mnA=fmaxf(mA,tmA), mnB=fmaxf(mB,tmB);
      float eaA=__expf(mA-mnA), eaB=__expf(mB-mnB);
      float cA[4], cB[4];
      #pragma unroll
      for(int u=0;u<4;u++){ cA[u]=__expf(sA[u]-mnA); cB[u]=__expf(sB[u]-mnB); }
      lA=lA*eaA+cA[0]+cA[1]+cA[2]+cA[3];
      lB=lB*eaB+cB[0]+cB[1]+cB[2]+cB[3];
      #pragma unroll
      for(int p=0;p<16;p++){ amA[p]*=eaA; amB[p]*=eaB; }
      asA0*=eaA; asA1*=eaA; asA2*=eaA; asB0*=eaB; asB1*=eaB; asB2*=eaB;
      mA=mnA; mB=mnB;
      #pragma unroll
      for(int u=0;u<4;u++){
        int r=rb+u*8;
        const float4* V4=(const float4*)&Vt[r*20];
        float4 v0=V4[0],v1=V4[1],v2=V4[2],v3=V4[3],v4=V4[4];
        float ca=cA[u], cb=cB[u];
        amA[0]+=ca*v0.x; amA[1]+=ca*v0.y; amA[2]+=ca*v0.z; amA[3]+=ca*v0.w;
        amA[4]+=ca*v1.x; amA[5]+=ca*v1.y; amA[6]+=ca*v1.z; amA[7]+=ca*v1.w;
        amA[8]+=ca*v2.x; amA[9]+=ca*v2.y; amA[10]+=ca*v2.z; amA[11]+=ca*v2.w;
        amA[12]+=ca*v3.x; amA[13]+=ca*v3.y; amA[14]+=ca*v3.z; amA[15]+=ca*v3.w;
        asA0+=ca*v4.x; asA1+=ca*v4.y; asA2+=ca*v4.z;
        amB[0]+=cb*v0.x; amB[1]+=cb*v0.y; amB[2]+=cb*v0.z; amB[3]+=cb*v0.w;
        amB[4]+=cb*v1.x; amB[5]+=cb*v1.y; amB[6]+=cb*v1.z; amB[7]+=cb*v1.w;
        amB[8]+=cb*v2.x; amB[9]+=cb*v2.y; amB[10]+=cb*v2.z; amB[11]+=cb*v2.w;
        amB[12]+=cb*v3.x; amB[13]+=cb*v3.y; amB[14]+=cb*v3.z; amB[15]+=cb*v3.w;
        asB0+=cb*v4.x; asB1+=cb*v4.y; asB2+=cb*v4.z;
      }
    }
    __syncthreads();
  }

  // butterfly merge across 8 key-lanes for both queries
  #pragma unroll
  for(int mk=1; mk<8; mk<<=1){
    float omA=__shfl_xor(mA,mk), olA=__shfl_xor(lA,mk);
    float omB=__shfl_xor(mB,mk), olB=__shfl_xor(lB,mk);
    float oaA[16], oaB[16];
    #pragma unroll
    for(int p=0;p<16;p++){ oaA[p]=__shfl_xor(amA[p],mk); oaB[p]=__shfl_xor(amB[p],mk); }
    float oA0=__shfl_xor(asA0,mk), oA1=__shfl_xor(asA1,mk), oA2=__shfl_xor(asA2,mk);
    float oB0=__shfl_xor(asB0,mk), oB1=__shfl_xor(asB1,mk), oB2=__shfl_xor(asB2,mk);
    float mnA=fmaxf(mA,omA), mnB=fmaxf(mB,omB);
    float aA=__expf(mA-mnA), bA=__expf(omA-mnA);
    float aB=__expf(mB-mnB), bB=__expf(omB-mnB);
    lA=lA*aA+olA*bA; lB=lB*aB+olB*bB;
    #pragma unroll
    for(int p=0;p<16;p++){ amA[p]=amA[p]*aA+oaA[p]*bA; amB[p]=amB[p]*aB+oaB[p]*bB; }
    asA0=asA0*aA+oA0*bA; asA1=asA1*aA+oA1*bA; asA2=asA2*aA+oA2*bA;
    asB0=asB0*aB+oB0*bB; asB1=asB1*aB+oB1*bB; asB2=asB2*aB+oB2*bB;
    mA=mnA; mB=mnB;
  }

  if(ki==0){
    float invA=1.f/lA, invB=1.f/lB;
    size_t tqA=(size_t)b*T_+qA, tqB=(size_t)b*T_+qB;
    float4* o4=(float4*)(o_mv+tqA*128+h*16);
    #pragma unroll
    for(int i=0;i<4;i++) o4[i]=make_float4(amA[i*4]*invA,amA[i*4+1]*invA,amA[i*4+2]*invA,amA[i*4+3]*invA);
    float* osp=o_s+tqA*24+h*3;
    osp[0]=asA0*invA; osp[1]=asA1*invA; osp[2]=asA2*invA;
    o4=(float4*)(o_mv+tqB*128+h*16);
    #pragma unroll
    for(int i=0;i<4;i++) o4[i]=make_float4(amB[i*4]*invB,amB[i*4+1]*invB,amB[i*4+2]*invB,amB[i*4+3]*invB);
    osp=o_s+tqB*24+h*3;
    osp[0]=asB0*invB; osp[1]=asB1*invB; osp[2]=asB2*invB;
  }
}

// ---- K_C: ao + residual + norm + m1 + GP/join + gate + m2 + out ----------
// 64 threads = 8 tokens x 8 channel-lanes. GP/JOIN tables built in LDS.
__global__ void __launch_bounds__(64) k_tail(
    const float* __restrict__ o_mv, const float* __restrict__ o_s,
    const float* __restrict__ w_ao_mv, const float* __restrict__ w_ao_s2mv,
    const float* __restrict__ w_ao_m2s, const float* __restrict__ w_ao_s2s,
    const float* __restrict__ b_ao_mv, const float* __restrict__ b_ao_s,
    const float* __restrict__ h_mv, const float* __restrict__ h_s,
    const float* __restrict__ w_m1_mv, const float* __restrict__ w_m1_s2mv,
    const float* __restrict__ w_m1_m2s, const float* __restrict__ w_m1_s2s,
    const float* __restrict__ b_m1_mv, const float* __restrict__ b_m1_s,
    const float* __restrict__ w_m2_mv, const float* __restrict__ w_m2_s2mv,
    const float* __restrict__ b_m2_mv,
    const float* __restrict__ w_out_mv,
    float* __restrict__ out)
{
  __shared__ int   GPI[256]; __shared__ float GPS[256];
  __shared__ int   JNI[256]; __shared__ float JNS[256];
  __shared__ float NS[8*152];
  __shared__ float U[8*264];
  __shared__ float G[8*136];
  __shared__ float GSm[8*24];
  int tid=threadIdx.x, tl=tid>>3, o=tid&7;
  int tt=blockIdx.x*8+tl;

  { // build tables (threads 0..31)
    const int mask_of[16]={0,1,2,4,8,3,5,9,6,10,12,7,11,13,14,15};
    const int idx_of[16] ={0,1,2,5,3,6,8,11,4,7,9,12,10,13,14,15};
    if (tid<16){
      int k=tid, km=mask_of[k], slot=0;
      for(int i=0;i<16;i++){
        int im=mask_of[i], jm=im^km;
        if(im & jm & 1) continue;
        GPI[k*16+slot]=i|(idx_of[jm]<<4);
        GPS[k*16+slot]=(float)rsign_d(im,jm);
        slot++;
      }
      for(;slot<16;slot++){ GPI[k*16+slot]=0; GPS[k*16+slot]=0.f; }
    } else if (tid<32){
      int p=tid-16, pm=mask_of[p], rest=15&~pm, slot=0;
      for(int u=0;u<16;u++){
        if(u & ~rest) continue;
        int am=pm|u, bm=pm|(rest&~u);
        float s=(float)( rsign_d(pm,15&~pm)*rsign_d(15&~am,15&~bm)
                        *rsign_d(am,15&~am)*rsign_d(bm,15&~bm) );
        JNI[p*16+slot]=idx_of[am]|(idx_of[bm]<<4);
        JNS[p*16+slot]=s;
        slot++;
      }
      for(;slot<16;slot++){ JNI[p*16+slot]=0; JNS[p*16+slot]=0.f; }
    }
  }

  float xm[8][16]; load_mv8(o_mv+(size_t)tt*128, xm);
  float xs[24];
  #pragma unroll
  for(int jj=0;jj<24;jj++) xs[jj]=o_s[(size_t)tt*24+jj];

  // ao linear, channel o + residual
  float y[16]; lin_one8(xm, w_ao_mv+o*72, y);
  float e=b_ao_mv[o];
  for(int jj=0;jj<24;jj++) e+=w_ao_s2mv[o*24+jj]*xs[jj];
  y[0]+=e;
  float hch[16]; float sqv=0.f;
  { const float4* hg=(const float4*)(h_mv+(size_t)tt*128+o*16);
    #pragma unroll
    for(int r4=0;r4<4;r4++){ float4 v=hg[r4];
      hch[r4*4]=v.x+y[r4*4]; hch[r4*4+1]=v.y+y[r4*4+1];
      hch[r4*4+2]=v.z+y[r4*4+2]; hch[r4*4+3]=v.w+y[r4*4+3]; } }
  #pragma unroll
  for(int p=0;p<16;p++) sqv+=FINNER[p]*hch[p]*hch[p];
  sqv+=__shfl_xor(sqv,1); sqv+=__shfl_xor(sqv,2); sqv+=__shfl_xor(sqv,4);
  float dmv=rsqrtf(sqv*0.125f+0.01f);

  float hs3[3]; float ssq=0.f;
  #pragma unroll
  for(int jj=0;jj<3;jj++){
    int d=o*3+jj;
    float a=b_ao_s[d];
    for(int i=0;i<8;i++) a+=w_ao_m2s[d*8+i]*xm[i][0];
    for(int j2=0;j2<24;j2++) a+=w_ao_s2s[d*24+j2]*xs[j2];
    float v=h_s[(size_t)tt*24+d]+a;
    hs3[jj]=v; ssq+=v*v;
  }
  ssq+=__shfl_xor(ssq,1); ssq+=__shfl_xor(ssq,2); ssq+=__shfl_xor(ssq,4);
  float dss=rsqrtf(ssq*(1.f/24.f)+0.01f);

  float* ns=&NS[tl*152];
  #pragma unroll
  for(int p=0;p<16;p++) ns[o*16+p]=hch[p]*dmv;
  #pragma unroll
  for(int jj=0;jj<3;jj++) ns[128+o*3+jj]=hs3[jj]*dss;
  __syncthreads();

  // m1: channels o and o+8
  float uA[16],uB[16];
  #pragma unroll
  for(int p=0;p<16;p++){ uA[p]=0.f; uB[p]=0.f; }
  float nx0[8];
  for(int i=0;i<8;i++){
    float xi[16];
    const float4* xs4=(const float4*)&ns[i*16];
    #pragma unroll
    for(int r4=0;r4<4;r4++){ float4 v=xs4[r4]; xi[r4*4]=v.x; xi[r4*4+1]=v.y; xi[r4*4+2]=v.z; xi[r4*4+3]=v.w; }
    nx0[i]=xi[0];
    const float* wA=w_m1_mv+o*72+i*9;
    const float* wB=w_m1_mv+(o+8)*72+i*9;
    #pragma unroll
    for(int p=0;p<16;p++){
      float bb=xi[p];
      uA[p]+=wA[GRADE[p]]*bb; uB[p]+=wB[GRADE[p]]*bb;
      if(AUGK[p]>=0){ float au=xi[AUGS[p]]; uA[p]+=wA[AUGK[p]]*au; uB[p]+=wB[AUGK[p]]*au; }
    }
  }
  float eA=b_m1_mv[o], eB=b_m1_mv[o+8];
  float s3[3];
  #pragma unroll
  for(int jj=0;jj<3;jj++) s3[jj]=b_m1_s[o*3+jj];
  for(int j2=0;j2<24;j2++){
    float s=ns[128+j2];
    eA+=w_m1_s2mv[o*24+j2]*s; eB+=w_m1_s2mv[(o+8)*24+j2]*s;
    #pragma unroll
    for(int jj=0;jj<3;jj++) s3[jj]+=w_m1_s2s[(o*3+jj)*24+j2]*s;
  }
  for(int i=0;i<8;i++){
    #pragma unroll
    for(int jj=0;jj<3;jj++) s3[jj]+=w_m1_m2s[(o*3+jj)*8+i]*nx0[i];
  }
  uA[0]+=eA; uB[0]+=eB;
  float* u=&U[tl*264];
  #pragma unroll
  for(int p=0;p<16;p++){ u[o*16+p]=uA[p]; u[(o+8)*16+p]=uB[p]; }
  float* gsm=&GSm[tl*24];
  #pragma unroll
  for(int jj=0;jj<3;jj++) gsm[o*3+jj]=gelu_f(s3[jj]);
  __syncthreads();

  // GP (o<4) / JOIN (o>=4), channel o
  const int*   TI=(o<4)? GPI : JNI;
  const float* TS=(o<4)? GPS : JNS;
  const float* lft=&u[((o<4)? o : (4+o))*16];
  const float* rgt=&u[((o<4)? (4+o) : (8+o))*16];
  float g[16];
  #pragma unroll
  for(int k=0;k<16;k++){
    float acc=0.f;
    #pragma unroll
    for(int e2=0;e2<16;e2++){
      int ij=TI[k*16+e2]; float sg=TS[k*16+e2];
      acc += sg * lft[ij&15] * rgt[ij>>4];
    }
    g[k]=acc;
  }
  float gt=gelu_f(g[0]);
  #pragma unroll
  for(int p=0;p<16;p++) g[p]*=gt;
  float* gg=&G[tl*136];
  #pragma unroll
  for(int p=0;p<16;p++) gg[o*16+p]=g[p];
  __syncthreads();

  // m2 channel o + residual + out projection
  float y2[16];
  #pragma unroll
  for(int p=0;p<16;p++) y2[p]=0.f;
  for(int i=0;i<8;i++){
    float xi[16];
    const float4* xs4=(const float4*)&gg[i*16 - o*16 + o*16];   // gg is token base + o*16; recompute base:
    (void)xs4;
    const float4* gi=(const float4*)&G[tl*136 + i*16];
    #pragma unroll
    for(int r4=0;r4<4;r4++){ float4 v=gi[r4]; xi[r4*4]=v.x; xi[r4*4+1]=v.y; xi[r4*4+2]=v.z; xi[r4*4+3]=v.w; }
    const float* wi=w_m2_mv+o*72+i*9;
    #pragma unroll
    for(int p=0;p<16;p++){
      y2[p]+=wi[GRADE[p]]*xi[p];
      if(AUGK[p]>=0) y2[p]+=wi[AUGK[p]]*xi[AUGS[p]];
    }
  }
  float e2=b_m2_mv[o];
  for(int j2=0;j2<24;j2++) e2+=w_m2_s2mv[o*24+j2]*gsm[j2];
  y2[0]+=e2;
  float hf[16];
  #pragma unroll
  for(int p=0;p<16;p++) hf[p]=hch[p]+y2[p];

  const float* wout=w_out_mv+o*9;
  float c5 =wout[2]*hf[5] +wout[6]*hf[2];
  float c6 =wout[2]*hf[6] +wout[6]*hf[3];
  float c7 =wout[2]*hf[7] +wout[6]*hf[4];
  float c11=wout[3]*hf[11]+wout[7]*hf[8];
  float c12=wout[3]*hf[12]+wout[7]*hf[9];
  float c13=wout[3]*hf[13]+wout[7]*hf[10];
  float c14=wout[3]*hf[14];
  #pragma unroll
  for(int mk=1; mk<8; mk<<=1){
    c5+=__shfl_xor(c5,mk); c6+=__shfl_xor(c6,mk); c7+=__shfl_xor(c7,mk);
    c11+=__shfl_xor(c11,mk); c12+=__shfl_xor(c12,mk);
    c13+=__shfl_xor(c13,mk); c14+=__shfl_xor(c14,mk);
  }
  if(o==0){
    float dd=c14;
    dd=(fabsf(dd)>0.001f)? dd : (dd>=0.f? 0.001f : -0.001f);
    float* op=out+(size_t)tt*6;
    op[0]=-c13/dd; op[1]=c12/dd; op[2]=-c11/dd;
    op[3]=2.f*c5; op[4]=2.f*c6; op[5]=2.f*c7;
  }
}

extern "C" void kernel_launch(void* const* d_in, const int* in_sizes, int n_in,
                              void* d_out, int out_size, void* d_ws, size_t ws_size,
                              hipStream_t stream)
{
  (void)in_sizes; (void)n_in; (void)out_size; (void)ws_size;
  const float* x         =(const float*)d_in[0];
  const float* w_in_mv   =(const float*)d_in[1];
  const float* b_in_mv   =(const float*)d_in[2];
  const float* w_in_m2s  =(const float*)d_in[3];
  const float* b_in_s    =(const float*)d_in[4];
  const float* w_qkv_mv  =(const float*)d_in[5];
  const float* w_qkv_s2mv=(const float*)d_in[6];
  const float* w_qkv_m2s =(const float*)d_in[7];
  const float* w_qkv_s2s =(const float*)d_in[8];
  const float* w_ao_mv   =(const float*)d_in[9];
  const float* w_ao_s2mv =(const float*)d_in[10];
  const float* w_ao_m2s  =(const float*)d_in[11];
  const float* w_ao_s2s  =(const float*)d_in[12];
  const float* b_ao_mv   =(const float*)d_in[13];
  const float* b_ao_s    =(const float*)d_in[14];
  const float* w_m1_mv   =(const float*)d_in[15];
  const float* w_m1_s2mv =(const float*)d_in[16];
  const float* w_m1_m2s  =(const float*)d_in[17];
  const float* w_m1_s2s  =(const float*)d_in[18];
  const float* b_m1_mv   =(const float*)d_in[19];
  const float* b_m1_s    =(const float*)d_in[20];
  const float* w_m2_mv   =(const float*)d_in[21];
  const float* w_m2_s2mv =(const float*)d_in[22];
  const float* b_m2_mv   =(const float*)d_in[25];
  const float* w_out_mv  =(const float*)d_in[27];
  float* outp=(float*)d_out;

  float* ws=(float*)d_ws;
  size_t off=0;
  float* h_mv = ws+off; off+=(size_t)BTOK*128;
  float* h_s  = ws+off; off+=(size_t)BTOK*24;
  float* o_mv = ws+off; off+=(size_t)BTOK*128;
  float* o_s  = ws+off; off+=(size_t)BTOK*24;
  float* qpk  = ws+off; off+=(size_t)16*T_*12;
  float* kpk  = ws+off; off+=(size_t)16*T_*12;
  float* vpk  = ws+off; off+=(size_t)16*T_*20;

  k_in  <<<BTOK/8,64,0,stream>>>(x,w_in_mv,b_in_mv,w_in_m2s,b_in_s,
                                 w_qkv_mv,w_qkv_s2mv,w_qkv_m2s,w_qkv_s2s,
                                 h_mv,h_s,qpk,kpk,vpk);
  k_attn<<<512,256,0,stream>>>(qpk,kpk,vpk,o_mv,o_s);
  k_tail<<<BTOK/8,64,0,stream>>>(o_mv,o_s,
                                 w_ao_mv,w_ao_s2mv,w_ao_m2s,w_ao_s2s,b_ao_mv,b_ao_s,
                                 h_mv,h_s,
                                 w_m1_mv,w_m1_s2mv,w_m1_m2s,w_m1_s2s,b_m1_mv,b_m1_s,
                                 w_m2_mv,w_m2_s2mv,b_m2_mv,w_out_mv,outp);
}

// Round 4
// 102.804 us; speedup vs baseline: 17.2379x; 1.6090x over previous
//
#include <hip/hip_runtime.h>
#include <math.h>

#define T_    2048
#define BTOK  4096   // B * T
#define KB    64

namespace {
constexpr int GRADE[16] = {0,1,1,1,1,2,2,2,2,2,2,3,3,3,3,4};
constexpr int AUGK[16]  = {-1,5,-1,-1,-1,6,6,6,-1,-1,-1,7,7,7,-1,8};
constexpr int AUGS[16]  = { 0,0, 0, 0, 0,2,3,4, 0, 0, 0,8,9,10,0,14};
constexpr float FINNER[16] = {1.f,0.f,1.f,1.f,1.f,0.f,0.f,0.f,1.f,1.f,1.f,0.f,0.f,0.f,1.f,0.f};
}

__device__ __forceinline__ float gelu_f(float v){
  return 0.5f*v*(1.f + erff(v*0.70710678118654752f));
}

__device__ __forceinline__ int rsign_d(int a, int b){
  int s=0; a>>=1; while(a){ s += __popc(a&b); a>>=1; } return (s&1) ? -1 : 1;
}

// ---- K_A: embed + in-linear + norm + QKV projections + pack --------------
// 64 threads = 4 tokens x 16 lanes (8 channels x 2 input-halves).
__global__ void __launch_bounds__(64) k_in(
    const float* __restrict__ x,
    const float* __restrict__ w_in_mv, const float* __restrict__ b_in_mv,
    const float* __restrict__ w_in_m2s, const float* __restrict__ b_in_s,
    const float* __restrict__ w_mv, const float* __restrict__ w_s2mv,
    const float* __restrict__ w_m2s, const float* __restrict__ w_s2s,
    float* __restrict__ h_mv, float* __restrict__ h_s,
    float* __restrict__ qp_, float* __restrict__ kp_, float* __restrict__ vp_)
{
  __shared__ float NS[4*152];   // per token: n_mv 128 + n_s 24
  int tid=threadIdx.x, tl=tid>>4, ln=tid&15;
  int o=ln&7, ih=ln>>3;
  int tt=blockIdx.x*4+tl;
  int b=tt>>11, t=tt&(T_-1);
  const float* xp = x+(size_t)tt*6;
  float mv[16];
  #pragma unroll
  for(int p=0;p<16;p++) mv[p]=0.f;
  mv[0]=1.f; mv[14]=1.f;
  mv[13]=-xp[0]; mv[12]=xp[1]; mv[11]=-xp[2];
  mv[5]=0.5f*xp[3]; mv[6]=0.5f*xp[4]; mv[7]=0.5f*xp[5];

  const float* wo=w_in_mv+o*9;
  float h[16]; float sq=0.f;
  #pragma unroll
  for(int p=0;p<16;p++){
    float v=wo[GRADE[p]]*mv[p];
    if(AUGK[p]>=0) v+=wo[AUGK[p]]*mv[AUGS[p]];
    if(p==0) v+=b_in_mv[o];
    h[p]=v; sq+=FINNER[p]*v*v;
  }
  sq+=__shfl_xor(sq,1); sq+=__shfl_xor(sq,2); sq+=__shfl_xor(sq,4);
  float dmv=rsqrtf(sq*0.125f+0.01f);
  float hs[3]; float ssq=0.f;
  #pragma unroll
  for(int jj=0;jj<3;jj++){ float v=w_in_m2s[o*3+jj]+b_in_s[o*3+jj]; hs[jj]=v; ssq+=v*v; }
  ssq+=__shfl_xor(ssq,1); ssq+=__shfl_xor(ssq,2); ssq+=__shfl_xor(ssq,4);
  float dss=rsqrtf(ssq*(1.f/24.f)+0.01f);

  float* ns=&NS[tl*152];
  if(ih==0){
    float4* hg=(float4*)(h_mv+(size_t)tt*128+o*16);
    hg[0]=make_float4(h[0],h[1],h[2],h[3]);
    hg[1]=make_float4(h[4],h[5],h[6],h[7]);
    hg[2]=make_float4(h[8],h[9],h[10],h[11]);
    hg[3]=make_float4(h[12],h[13],h[14],h[15]);
    #pragma unroll
    for(int jj=0;jj<3;jj++) h_s[(size_t)tt*24+o*3+jj]=hs[jj];
    #pragma unroll
    for(int p=0;p<16;p++) ns[o*16+p]=h[p]*dmv;
    #pragma unroll
    for(int jj=0;jj<3;jj++) ns[128+o*3+jj]=hs[jj]*dss;
  }
  __syncthreads();

  // projections: lane (o, ih) does input channels ih*4..+4, scalar j ih*12..+12
  float yq[16],yk[16],yv[16];
  #pragma unroll
  for(int p=0;p<16;p++){ yq[p]=0.f; yk[p]=0.f; yv[p]=0.f; }
  float nx0p[4];
  const float* wq=w_mv+o*72;
  #pragma unroll
  for(int ii=0;ii<4;ii++){
    int i=ih*4+ii;
    float xi[16];
    const float4* xs4=(const float4*)&ns[i*16];
    #pragma unroll
    for(int r4=0;r4<4;r4++){ float4 v=xs4[r4]; xi[r4*4]=v.x; xi[r4*4+1]=v.y; xi[r4*4+2]=v.z; xi[r4*4+3]=v.w; }
    nx0p[ii]=xi[0];
    const float* aq=wq+i*9; const float* ak=aq+576; const float* av=aq+1152;
    #pragma unroll
    for(int p=0;p<16;p++){
      float bb=xi[p];
      yq[p]+=aq[GRADE[p]]*bb; yk[p]+=ak[GRADE[p]]*bb; yv[p]+=av[GRADE[p]]*bb;
      if(AUGK[p]>=0){
        float au=xi[AUGS[p]];
        yq[p]+=aq[AUGK[p]]*au; yk[p]+=ak[AUGK[p]]*au; yv[p]+=av[AUGK[p]]*au;
      }
    }
  }
  float eq=0.f,ek=0.f,ev=0.f;
  float sq3[3]={0,0,0}, sk3[3]={0,0,0}, sv3[3]={0,0,0};
  for(int j=ih*12;j<ih*12+12;j++){
    float s=ns[128+j];
    eq+=w_s2mv[o*24+j]*s; ek+=w_s2mv[192+o*24+j]*s; ev+=w_s2mv[384+o*24+j]*s;
    #pragma unroll
    for(int jj=0;jj<3;jj++){
      int d=o*3+jj;
      sq3[jj]+=w_s2s[d*24+j]*s;
      sk3[jj]+=w_s2s[576+d*24+j]*s;
      sv3[jj]+=w_s2s[1152+d*24+j]*s;
    }
  }
  #pragma unroll
  for(int ii=0;ii<4;ii++){
    int i=ih*4+ii;
    #pragma unroll
    for(int jj=0;jj<3;jj++){
      int d=o*3+jj;
      sq3[jj]+=w_m2s[d*8+i]*nx0p[ii];
      sk3[jj]+=w_m2s[192+d*8+i]*nx0p[ii];
      sv3[jj]+=w_m2s[384+d*8+i]*nx0p[ii];
    }
  }
  yq[0]+=eq; yk[0]+=ek; yv[0]+=ev;
  // combine the two halves
  #pragma unroll
  for(int p=0;p<16;p++){
    yq[p]+=__shfl_xor(yq[p],8);
    yk[p]+=__shfl_xor(yk[p],8);
    yv[p]+=__shfl_xor(yv[p],8);
  }
  #pragma unroll
  for(int jj=0;jj<3;jj++){
    sq3[jj]+=__shfl_xor(sq3[jj],8);
    sk3[jj]+=__shfl_xor(sk3[jj],8);
    sv3[jj]+=__shfl_xor(sv3[jj],8);
  }

  const float scale = 0.3015113445777636f;  // 1/sqrt(11)
  size_t rb=((size_t)(b*8+o)*T_+t);
  if(ih==0){
    float4* qr=(float4*)(qp_+rb*12);
    qr[0]=make_float4(yq[0]*scale, yq[2]*scale, yq[3]*scale, yq[4]*scale);
    qr[1]=make_float4(yq[8]*scale, yq[9]*scale, yq[10]*scale, yq[14]*scale);
    qr[2]=make_float4(sq3[0]*scale, sq3[1]*scale, sq3[2]*scale, 0.f);
    float4* vr=(float4*)(vp_+rb*20);
    vr[0]=make_float4(yv[0],yv[1],yv[2],yv[3]);
    vr[1]=make_float4(yv[4],yv[5],yv[6],yv[7]);
    vr[2]=make_float4(yv[8],yv[9],yv[10],yv[11]);
  } else {
    float4* kr=(float4*)(kp_+rb*12);
    kr[0]=make_float4(yk[0],yk[2],yk[3],yk[4]);
    kr[1]=make_float4(yk[8],yk[9],yk[10],yk[14]);
    kr[2]=make_float4(sk3[0],sk3[1],sk3[2],0.f);
    float4* vr=(float4*)(vp_+rb*20);
    vr[3]=make_float4(yv[12],yv[13],yv[14],yv[15]);
    vr[4]=make_float4(sv3[0],sv3[1],sv3[2],0.f);
  }
}

// ---- K_B: attention, flash-decoding split over key range -----------------
// 1024 blocks: bh x 32 q-strips x 2 key-splits. Un-normalized partials out.
__global__ void __launch_bounds__(256) k_attn(
    const float* __restrict__ qp_, const float* __restrict__ kp_,
    const float* __restrict__ vp_,
    float* __restrict__ part)
{
  __shared__ float Kt[KB*12];
  __shared__ float Vt[KB*20];
  int tid=threadIdx.x; int qi=tid>>3, ki=tid&7;
  int j=blockIdx.x;
  int bh = j & 15;
  int idx = j>>4;                 // 0..63
  int qs = 31 - (idx>>1);        // heavy strips first
  int sp = idx&1;
  int q0=qs*64;
  int qA=q0+qi, qB=q0+32+qi;
  int ntiles=qs+1, half=(ntiles+1)>>1;
  int t0 = sp? half : 0;
  int t1 = sp? ntiles : half;

  float qpA[12], qpB[12];
  { const float4* p4=(const float4*)(qp_+((size_t)bh*T_+qA)*12);
    #pragma unroll
    for(int i=0;i<3;i++){ float4 v=p4[i]; qpA[i*4]=v.x; qpA[i*4+1]=v.y; qpA[i*4+2]=v.z; qpA[i*4+3]=v.w; } }
  { const float4* p4=(const float4*)(qp_+((size_t)bh*T_+qB)*12);
    #pragma unroll
    for(int i=0;i<3;i++){ float4 v=p4[i]; qpB[i*4]=v.x; qpB[i*4+1]=v.y; qpB[i*4+2]=v.z; qpB[i*4+3]=v.w; } }

  int kendA=(qA&~15)+16, kendB=(qB&~15)+16;
  float mA=-1e30f,lA=0.f, mB=-1e30f,lB=0.f;
  float amA[16], amB[16];
  #pragma unroll
  for(int p=0;p<16;p++){ amA[p]=0.f; amB[p]=0.f; }
  float asA0=0.f,asA1=0.f,asA2=0.f, asB0=0.f,asB1=0.f,asB2=0.f;

  const float4* gk=(const float4*)(kp_+(size_t)bh*T_*12);
  const float4* gv=(const float4*)(vp_+(size_t)bh*T_*20);

  for(int tile=t0; tile<t1; ++tile){
    int s0=tile*KB;
    int i1=tid, i2=tid+256;
    if(i1<192) ((float4*)Kt)[i1]=gk[s0*3+i1];
    else       ((float4*)Vt)[i1-192]=gv[s0*5+(i1-192)];
    ((float4*)Vt)[i2-192]=gv[s0*5+(i2-192)];
    __syncthreads();
    #pragma unroll
    for(int g=0; g<2; ++g){
      int rb=ki+g*32;
      float sA[4], sB[4];
      #pragma unroll
      for(int u=0;u<4;u++){
        int r=rb+u*8;
        const float4* K4=(const float4*)&Kt[r*12];
        float4 k0=K4[0],k1=K4[1],k2=K4[2];
        float dA = qpA[0]*k0.x+qpA[1]*k0.y+qpA[2]*k0.z+qpA[3]*k0.w
                 + qpA[4]*k1.x+qpA[5]*k1.y+qpA[6]*k1.z+qpA[7]*k1.w
                 + qpA[8]*k2.x+qpA[9]*k2.y+qpA[10]*k2.z;
        float dB = qpB[0]*k0.x+qpB[1]*k0.y+qpB[2]*k0.z+qpB[3]*k0.w
                 + qpB[4]*k1.x+qpB[5]*k1.y+qpB[6]*k1.z+qpB[7]*k1.w
                 + qpB[8]*k2.x+qpB[9]*k2.y+qpB[10]*k2.z;
        int s=s0+r;
        sA[u]=(s<kendA)? dA : -1e30f;
        sB[u]=(s<kendB)? dB : -1e30f;
      }
      float tmA=fmaxf(fmaxf(sA[0],sA[1]),fmaxf(sA[2],sA[3]));
      float tmB=fmaxf(fmaxf(sB[0],sB[1]),fmaxf(sB[2],sB[3]));
      float mnA=fmaxf(mA,tmA), mnB=fmaxf(mB,tmB);
      float eaA=__expf(mA-mnA), eaB=__expf(mB-mnB);
      float cA[4], cB[4];
      #pragma unroll
      for(int u=0;u<4;u++){ cA[u]=__expf(sA[u]-mnA); cB[u]=__expf(sB[u]-mnB); }
      lA=lA*eaA+cA[0]+cA[1]+cA[2]+cA[3];
      lB=lB*eaB+cB[0]+cB[1]+cB[2]+cB[3];
      #pragma unroll
      for(int p=0;p<16;p++){ amA[p]*=eaA; amB[p]*=eaB; }
      asA0*=eaA; asA1*=eaA; asA2*=eaA; asB0*=eaB; asB1*=eaB; asB2*=eaB;
      mA=mnA; mB=mnB;
      #pragma unroll
      for(int u=0;u<4;u++){
        int r=rb+u*8;
        const float4* V4=(const float4*)&Vt[r*20];
        float4 v0=V4[0],v1=V4[1],v2=V4[2],v3=V4[3],v4=V4[4];
        float ca=cA[u], cb=cB[u];
        amA[0]+=ca*v0.x; amA[1]+=ca*v0.y; amA[2]+=ca*v0.z; amA[3]+=ca*v0.w;
        amA[4]+=ca*v1.x; amA[5]+=ca*v1.y; amA[6]+=ca*v1.z; amA[7]+=ca*v1.w;
        amA[8]+=ca*v2.x; amA[9]+=ca*v2.y; amA[10]+=ca*v2.z; amA[11]+=ca*v2.w;
        amA[12]+=ca*v3.x; amA[13]+=ca*v3.y; amA[14]+=ca*v3.z; amA[15]+=ca*v3.w;
        asA0+=ca*v4.x; asA1+=ca*v4.y; asA2+=ca*v4.z;
        amB[0]+=cb*v0.x; amB[1]+=cb*v0.y; amB[2]+=cb*v0.z; amB[3]+=cb*v0.w;
        amB[4]+=cb*v1.x; amB[5]+=cb*v1.y; amB[6]+=cb*v1.z; amB[7]+=cb*v1.w;
        amB[8]+=cb*v2.x; amB[9]+=cb*v2.y; amB[10]+=cb*v2.z; amB[11]+=cb*v2.w;
        amB[12]+=cb*v3.x; amB[13]+=cb*v3.y; amB[14]+=cb*v3.z; amB[15]+=cb*v3.w;
        asB0+=cb*v4.x; asB1+=cb*v4.y; asB2+=cb*v4.z;
      }
    }
    __syncthreads();
  }

  // butterfly merge across 8 key-lanes
  #pragma unroll
  for(int mk=1; mk<8; mk<<=1){
    float omA=__shfl_xor(mA,mk), olA=__shfl_xor(lA,mk);
    float omB=__shfl_xor(mB,mk), olB=__shfl_xor(lB,mk);
    float oaA[16], oaB[16];
    #pragma unroll
    for(int p=0;p<16;p++){ oaA[p]=__shfl_xor(amA[p],mk); oaB[p]=__shfl_xor(amB[p],mk); }
    float oA0=__shfl_xor(asA0,mk), oA1=__shfl_xor(asA1,mk), oA2=__shfl_xor(asA2,mk);
    float oB0=__shfl_xor(asB0,mk), oB1=__shfl_xor(asB1,mk), oB2=__shfl_xor(asB2,mk);
    float mnA=fmaxf(mA,omA), mnB=fmaxf(mB,omB);
    float aA=__expf(mA-mnA), bA=__expf(omA-mnA);
    float aB=__expf(mB-mnB), bB=__expf(omB-mnB);
    lA=lA*aA+olA*bA; lB=lB*aB+olB*bB;
    #pragma unroll
    for(int p=0;p<16;p++){ amA[p]=amA[p]*aA+oaA[p]*bA; amB[p]=amB[p]*aB+oaB[p]*bB; }
    asA0=asA0*aA+oA0*bA; asA1=asA1*aA+oA1*bA; asA2=asA2*aA+oA2*bA;
    asB0=asB0*aB+oB0*bB; asB1=asB1*aB+oB1*bB; asB2=asB2*aB+oB2*bB;
    mA=mnA; mB=mnB;
  }

  if(ki==0){
    float* pA = part + ((size_t)(bh*T_+qA)*2+sp)*24;
    float4* pA4=(float4*)pA;
    pA4[0]=make_float4(amA[0],amA[1],amA[2],amA[3]);
    pA4[1]=make_float4(amA[4],amA[5],amA[6],amA[7]);
    pA4[2]=make_float4(amA[8],amA[9],amA[10],amA[11]);
    pA4[3]=make_float4(amA[12],amA[13],amA[14],amA[15]);
    pA4[4]=make_float4(mA,lA,asA0,asA1);
    pA[20]=asA2;
    float* pB = part + ((size_t)(bh*T_+qB)*2+sp)*24;
    float4* pB4=(float4*)pB;
    pB4[0]=make_float4(amB[0],amB[1],amB[2],amB[3]);
    pB4[1]=make_float4(amB[4],amB[5],amB[6],amB[7]);
    pB4[2]=make_float4(amB[8],amB[9],amB[10],amB[11]);
    pB4[3]=make_float4(amB[12],amB[13],amB[14],amB[15]);
    pB4[4]=make_float4(mB,lB,asB0,asB1);
    pB[20]=asB2;
  }
}

// ---- combine the 2 key-split partials ------------------------------------
__global__ void __launch_bounds__(256) k_comb(
    const float* __restrict__ part,
    float* __restrict__ o_mv, float* __restrict__ o_s)
{
  int gid=blockIdx.x*256+threadIdx.x;   // 32768 = 16 bh x 2048 q
  int bh=gid>>11, q=gid&2047;
  int b=bh>>3, h=bh&7;
  const float* p0=part + ((size_t)(bh*T_+q)*2+0)*24;
  const float* p1=part + ((size_t)(bh*T_+q)*2+1)*24;
  const float4* p04=(const float4*)p0;
  const float4* p14=(const float4*)p1;
  float4 meta0=p04[4], meta1=p14[4];
  float m0=meta0.x, l0=meta0.y, m1=meta1.x, l1=meta1.y;
  float mn=fmaxf(m0,m1);
  float w0=__expf(m0-mn), w1=__expf(m1-mn);
  float l=l0*w0+l1*w1;
  float inv=1.f/l;
  size_t tq=(size_t)b*T_+q;
  float4* o4=(float4*)(o_mv+tq*128+h*16);
  #pragma unroll
  for(int i=0;i<4;i++){
    float4 a=p04[i], c=p14[i];
    o4[i]=make_float4((a.x*w0+c.x*w1)*inv,(a.y*w0+c.y*w1)*inv,
                      (a.z*w0+c.z*w1)*inv,(a.w*w0+c.w*w1)*inv);
  }
  float* osp=o_s+tq*24+h*3;
  osp[0]=(meta0.z*w0+meta1.z*w1)*inv;
  osp[1]=(meta0.w*w0+meta1.w*w1)*inv;
  osp[2]=(p0[20]*w0+p1[20]*w1)*inv;
}

// ---- K_C: ao + residual + norm + m1 + GP/join + gate + m2 + out ----------
// 64 threads = 4 tokens x 16 lanes. Tables built in LDS.
__global__ void __launch_bounds__(64) k_tail(
    const float* __restrict__ o_mv, const float* __restrict__ o_s,
    const float* __restrict__ w_ao_mv, const float* __restrict__ w_ao_s2mv,
    const float* __restrict__ w_ao_m2s, const float* __restrict__ w_ao_s2s,
    const float* __restrict__ b_ao_mv, const float* __restrict__ b_ao_s,
    const float* __restrict__ h_mv, const float* __restrict__ h_s,
    const float* __restrict__ w_m1_mv, const float* __restrict__ w_m1_s2mv,
    const float* __restrict__ w_m1_m2s, const float* __restrict__ w_m1_s2s,
    const float* __restrict__ b_m1_mv, const float* __restrict__ b_m1_s,
    const float* __restrict__ w_m2_mv, const float* __restrict__ w_m2_s2mv,
    const float* __restrict__ b_m2_mv,
    const float* __restrict__ w_out_mv,
    float* __restrict__ out)
{
  __shared__ int   GPI[256]; __shared__ float GPS[256];
  __shared__ int   JNI[256]; __shared__ float JNS[256];
  __shared__ float NS[4*152];
  __shared__ float U[4*264];
  __shared__ float G[4*136];
  __shared__ float GSm[4*24];
  int tid=threadIdx.x, tl=tid>>4, ln=tid&15;
  int o=ln&7, ih=ln>>3;
  int tt=blockIdx.x*4+tl;

  { // build tables (threads 0..31)
    const int mask_of[16]={0,1,2,4,8,3,5,9,6,10,12,7,11,13,14,15};
    const int idx_of[16] ={0,1,2,5,3,6,8,11,4,7,9,12,10,13,14,15};
    if (tid<16){
      int k=tid, km=mask_of[k], slot=0;
      for(int i=0;i<16;i++){
        int im=mask_of[i], jm=im^km;
        if(im & jm & 1) continue;
        GPI[k*16+slot]=i|(idx_of[jm]<<4);
        GPS[k*16+slot]=(float)rsign_d(im,jm);
        slot++;
      }
      for(;slot<16;slot++){ GPI[k*16+slot]=0; GPS[k*16+slot]=0.f; }
    } else if (tid<32){
      int p=tid-16, pm=mask_of[p], rest=15&~pm, slot=0;
      for(int u=0;u<16;u++){
        if(u & ~rest) continue;
        int am=pm|u, bm=pm|(rest&~u);
        float s=(float)( rsign_d(pm,15&~pm)*rsign_d(15&~am,15&~bm)
                        *rsign_d(am,15&~am)*rsign_d(bm,15&~bm) );
        JNI[p*16+slot]=idx_of[am]|(idx_of[bm]<<4);
        JNS[p*16+slot]=s;
        slot++;
      }
      for(;slot<16;slot++){ JNI[p*16+slot]=0; JNS[p*16+slot]=0.f; }
    }
  }

  // own-half input channels of o_mv, full o_s
  float xh[4][16];
  #pragma unroll
  for(int ii=0;ii<4;ii++){
    const float4* g4=(const float4*)(o_mv+(size_t)tt*128+(ih*4+ii)*16);
    #pragma unroll
    for(int r4=0;r4<4;r4++){ float4 v=g4[r4];
      xh[ii][r4*4]=v.x; xh[ii][r4*4+1]=v.y; xh[ii][r4*4+2]=v.z; xh[ii][r4*4+3]=v.w; }
  }
  float xs[24];
  { const float4* s4=(const float4*)(o_s+(size_t)tt*24);
    #pragma unroll
    for(int r4=0;r4<6;r4++){ float4 v=s4[r4];
      xs[r4*4]=v.x; xs[r4*4+1]=v.y; xs[r4*4+2]=v.z; xs[r4*4+3]=v.w; } }

  // ao: channel o, partial over i-half and j-half
  float y[16];
  #pragma unroll
  for(int p=0;p<16;p++) y[p]=0.f;
  #pragma unroll
  for(int ii=0;ii<4;ii++){
    const float* wi=w_ao_mv+o*72+(ih*4+ii)*9;
    #pragma unroll
    for(int p=0;p<16;p++){
      y[p]+=wi[GRADE[p]]*xh[ii][p];
      if(AUGK[p]>=0) y[p]+=wi[AUGK[p]]*xh[ii][AUGS[p]];
    }
  }
  float e=(ih==0)? b_ao_mv[o] : 0.f;
  for(int j2=ih*12;j2<ih*12+12;j2++) e+=w_ao_s2mv[o*24+j2]*xs[j2];
  y[0]+=e;
  float a3[3];
  #pragma unroll
  for(int jj=0;jj<3;jj++) a3[jj]=(ih==0)? b_ao_s[o*3+jj] : 0.f;
  #pragma unroll
  for(int ii=0;ii<4;ii++){
    #pragma unroll
    for(int jj=0;jj<3;jj++) a3[jj]+=w_ao_m2s[(o*3+jj)*8+(ih*4+ii)]*xh[ii][0];
  }
  for(int j2=ih*12;j2<ih*12+12;j2++){
    #pragma unroll
    for(int jj=0;jj<3;jj++) a3[jj]+=w_ao_s2s[(o*3+jj)*24+j2]*xs[j2];
  }
  #pragma unroll
  for(int p=0;p<16;p++) y[p]+=__shfl_xor(y[p],8);
  #pragma unroll
  for(int jj=0;jj<3;jj++) a3[jj]+=__shfl_xor(a3[jj],8);

  // residual + norms (dup across halves; reduce within 8-lane groups)
  float hch[16]; float sqv=0.f;
  { const float4* hg=(const float4*)(h_mv+(size_t)tt*128+o*16);
    #pragma unroll
    for(int r4=0;r4<4;r4++){ float4 v=hg[r4];
      hch[r4*4]=v.x+y[r4*4]; hch[r4*4+1]=v.y+y[r4*4+1];
      hch[r4*4+2]=v.z+y[r4*4+2]; hch[r4*4+3]=v.w+y[r4*4+3]; } }
  #pragma unroll
  for(int p=0;p<16;p++) sqv+=FINNER[p]*hch[p]*hch[p];
  sqv+=__shfl_xor(sqv,1); sqv+=__shfl_xor(sqv,2); sqv+=__shfl_xor(sqv,4);
  float dmv=rsqrtf(sqv*0.125f+0.01f);
  float hs3[3]; float ssq=0.f;
  #pragma unroll
  for(int jj=0;jj<3;jj++){
    float v=h_s[(size_t)tt*24+o*3+jj]+a3[jj];
    hs3[jj]=v; ssq+=v*v;
  }
  ssq+=__shfl_xor(ssq,1); ssq+=__shfl_xor(ssq,2); ssq+=__shfl_xor(ssq,4);
  float dss=rsqrtf(ssq*(1.f/24.f)+0.01f);

  float* ns=&NS[tl*152];
  if(ih==0){
    #pragma unroll
    for(int p=0;p<16;p++) ns[o*16+p]=hch[p]*dmv;
    #pragma unroll
    for(int jj=0;jj<3;jj++) ns[128+o*3+jj]=hs3[jj]*dss;
  }
  __syncthreads();

  // m1: lane = output channel c=0..15
  float u[16];
  #pragma unroll
  for(int p=0;p<16;p++) u[p]=0.f;
  for(int i=0;i<8;i++){
    float xi[16];
    const float4* xs4=(const float4*)&ns[i*16];
    #pragma unroll
    for(int r4=0;r4<4;r4++){ float4 v=xs4[r4]; xi[r4*4]=v.x; xi[r4*4+1]=v.y; xi[r4*4+2]=v.z; xi[r4*4+3]=v.w; }
    const float* wi=w_m1_mv+ln*72+i*9;
    #pragma unroll
    for(int p=0;p<16;p++){
      u[p]+=wi[GRADE[p]]*xi[p];
      if(AUGK[p]>=0) u[p]+=wi[AUGK[p]]*xi[AUGS[p]];
    }
  }
  float e1=b_m1_mv[ln];
  for(int j2=0;j2<24;j2++) e1+=w_m1_s2mv[ln*24+j2]*ns[128+j2];
  u[0]+=e1;
  { float* uu=&U[tl*264];
    #pragma unroll
    for(int p=0;p<16;p++) uu[ln*16+p]=u[p]; }
  if(ih==0){
    float s3[3];
    #pragma unroll
    for(int jj=0;jj<3;jj++) s3[jj]=b_m1_s[o*3+jj];
    for(int j2=0;j2<24;j2++){
      float s=ns[128+j2];
      #pragma unroll
      for(int jj=0;jj<3;jj++) s3[jj]+=w_m1_s2s[(o*3+jj)*24+j2]*s;
    }
    for(int i=0;i<8;i++){
      float x0=ns[i*16];
      #pragma unroll
      for(int jj=0;jj<3;jj++) s3[jj]+=w_m1_m2s[(o*3+jj)*8+i]*x0;
    }
    #pragma unroll
    for(int jj=0;jj<3;jj++) GSm[tl*24+o*3+jj]=gelu_f(s3[jj]);
  }
  __syncthreads();

  // GP (o<4) / JOIN (o>=4): product o, component half ih
  { const int*   TI=(o<4)? GPI : JNI;
    const float* TS=(o<4)? GPS : JNS;
    const float* uu=&U[tl*264];
    const float* lft=&uu[((o<4)? o : (4+o))*16];
    const float* rgt=&uu[((o<4)? (4+o) : (8+o))*16];
    float* gg=&G[tl*136];
    #pragma unroll
    for(int kk=0;kk<8;kk++){
      int k=ih*8+kk;
      float acc=0.f;
      #pragma unroll
      for(int e2=0;e2<16;e2++){
        int ij=TI[k*16+e2]; float sg=TS[k*16+e2];
        acc += sg * lft[ij&15] * rgt[ij>>4];
      }
      gg[o*16+k]=acc;
    }
  }
  __syncthreads();
  // gate in place (lanes ih==0)
  if(ih==0){
    float* gg=&G[tl*136];
    float gt=gelu_f(gg[o*16]);
    #pragma unroll
    for(int p=0;p<16;p++) gg[o*16+p]*=gt;
  }
  __syncthreads();

  // m2: channel o, i-half + j-half, combine
  float y2[16];
  #pragma unroll
  for(int p=0;p<16;p++) y2[p]=0.f;
  #pragma unroll
  for(int ii=0;ii<4;ii++){
    float xi[16];
    const float4* gi=(const float4*)&G[tl*136+(ih*4+ii)*16];
    #pragma unroll
    for(int r4=0;r4<4;r4++){ float4 v=gi[r4]; xi[r4*4]=v.x; xi[r4*4+1]=v.y; xi[r4*4+2]=v.z; xi[r4*4+3]=v.w; }
    const float* wi=w_m2_mv+o*72+(ih*4+ii)*9;
    #pragma unroll
    for(int p=0;p<16;p++){
      y2[p]+=wi[GRADE[p]]*xi[p];
      if(AUGK[p]>=0) y2[p]+=wi[AUGK[p]]*xi[AUGS[p]];
    }
  }
  float e2=(ih==0)? b_m2_mv[o] : 0.f;
  for(int j2=ih*12;j2<ih*12+12;j2++) e2+=w_m2_s2mv[o*24+j2]*GSm[tl*24+j2];
  y2[0]+=e2;
  #pragma unroll
  for(int p=0;p<16;p++) y2[p]+=__shfl_xor(y2[p],8);

  float hf[16];
  #pragma unroll
  for(int p=0;p<16;p++) hf[p]=hch[p]+y2[p];

  const float* wout=w_out_mv+o*9;
  float c5 =wout[2]*hf[5] +wout[6]*hf[2];
  float c6 =wout[2]*hf[6] +wout[6]*hf[3];
  float c7 =wout[2]*hf[7] +wout[6]*hf[4];
  float c11=wout[3]*hf[11]+wout[7]*hf[8];
  float c12=wout[3]*hf[12]+wout[7]*hf[9];
  float c13=wout[3]*hf[13]+wout[7]*hf[10];
  float c14=wout[3]*hf[14];
  #pragma unroll
  for(int mk=1; mk<8; mk<<=1){
    c5+=__shfl_xor(c5,mk); c6+=__shfl_xor(c6,mk); c7+=__shfl_xor(c7,mk);
    c11+=__shfl_xor(c11,mk); c12+=__shfl_xor(c12,mk);
    c13+=__shfl_xor(c13,mk); c14+=__shfl_xor(c14,mk);
  }
  if(ln==0){
    float dd=c14;
    dd=(fabsf(dd)>0.001f)? dd : (dd>=0.f? 0.001f : -0.001f);
    float* op=out+(size_t)tt*6;
    op[0]=-c13/dd; op[1]=c12/dd; op[2]=-c11/dd;
    op[3]=2.f*c5; op[4]=2.f*c6; op[5]=2.f*c7;
  }
}

extern "C" void kernel_launch(void* const* d_in, const int* in_sizes, int n_in,
                              void* d_out, int out_size, void* d_ws, size_t ws_size,
                              hipStream_t stream)
{
  (void)in_sizes; (void)n_in; (void)out_size; (void)ws_size;
  const float* x         =(const float*)d_in[0];
  const float* w_in_mv   =(const float*)d_in[1];
  const float* b_in_mv   =(const float*)d_in[2];
  const float* w_in_m2s  =(const float*)d_in[3];
  const float* b_in_s    =(const float*)d_in[4];
  const float* w_qkv_mv  =(const float*)d_in[5];
  const float* w_qkv_s2mv=(const float*)d_in[6];
  const float* w_qkv_m2s =(const float*)d_in[7];
  const float* w_qkv_s2s =(const float*)d_in[8];
  const float* w_ao_mv   =(const float*)d_in[9];
  const float* w_ao_s2mv =(const float*)d_in[10];
  const float* w_ao_m2s  =(const float*)d_in[11];
  const float* w_ao_s2s  =(const float*)d_in[12];
  const float* b_ao_mv   =(const float*)d_in[13];
  const float* b_ao_s    =(const float*)d_in[14];
  const float* w_m1_mv   =(const float*)d_in[15];
  const float* w_m1_s2mv =(const float*)d_in[16];
  const float* w_m1_m2s  =(const float*)d_in[17];
  const float* w_m1_s2s  =(const float*)d_in[18];
  const float* b_m1_mv   =(const float*)d_in[19];
  const float* b_m1_s    =(const float*)d_in[20];
  const float* w_m2_mv   =(const float*)d_in[21];
  const float* w_m2_s2mv =(const float*)d_in[22];
  const float* b_m2_mv   =(const float*)d_in[25];
  const float* w_out_mv  =(const float*)d_in[27];
  float* outp=(float*)d_out;

  float* ws=(float*)d_ws;
  size_t off=0;
  float* h_mv = ws+off; off+=(size_t)BTOK*128;
  float* h_s  = ws+off; off+=(size_t)BTOK*24;
  float* o_mv = ws+off; off+=(size_t)BTOK*128;
  float* o_s  = ws+off; off+=(size_t)BTOK*24;
  float* qpk  = ws+off; off+=(size_t)16*T_*12;
  float* kpk  = ws+off; off+=(size_t)16*T_*12;
  float* vpk  = ws+off; off+=(size_t)16*T_*20;
  float* part = ws+off; off+=(size_t)16*T_*2*24;

  k_in  <<<BTOK/4,64,0,stream>>>(x,w_in_mv,b_in_mv,w_in_m2s,b_in_s,
                                 w_qkv_mv,w_qkv_s2mv,w_qkv_m2s,w_qkv_s2s,
                                 h_mv,h_s,qpk,kpk,vpk);
  k_attn<<<1024,256,0,stream>>>(qpk,kpk,vpk,part);
  k_comb<<<128,256,0,stream>>>(part,o_mv,o_s);
  k_tail<<<BTOK/4,64,0,stream>>>(o_mv,o_s,
                                 w_ao_mv,w_ao_s2mv,w_ao_m2s,w_ao_s2s,b_ao_mv,b_ao_s,
                                 h_mv,h_s,
                                 w_m1_mv,w_m1_s2mv,w_m1_m2s,w_m1_s2s,b_m1_mv,b_m1_s,
                                 w_m2_mv,w_m2_s2mv,b_m2_mv,w_out_mv,outp);
}